// Round 3
// baseline (12601.057 us; speedup 1.0000x reference)
//
#include <hip/hip_runtime.h>
#include <hip/hip_bf16.h>
#include <math.h>

// Problem constants (B=8, H=W=256, K=11 taps, thresh 0.2)
#define HH 256
#define WW 256
#define HW (HH*WW)
#define BB 8

typedef __hip_bfloat16 bf16;

// ---------------------------------------------------------------------------
// conv1: 3x3 SAME conv over concat(rgb,depth) [4ch f32 in], bf16 out, ReLU.
// Per-batch: processes image b only. Block = 256 threads = 64x4 pixel tile.
// ---------------------------------------------------------------------------
template<int COC>
__global__ __launch_bounds__(256) void conv3x3_first(const float* __restrict__ rgb,
                                                     const float* __restrict__ depth,
                                                     const float* __restrict__ w,
                                                     const float* __restrict__ bias,
                                                     bf16* __restrict__ out, int b)
{
    const int tid = threadIdx.x;
    const int x = blockIdx.x * 64 + (tid & 63);
    const int y = blockIdx.y * 4 + (tid >> 6);
    const int cog = blockIdx.z * COC;

    const bool vy0 = (y > 0), vy2 = (y < HH - 1);
    const bool vx0 = (x > 0), vx2 = (x < WW - 1);
    bool val[9];
    int  off[9];
    {
        int t = 0;
        for (int dy = -1; dy <= 1; ++dy)
            for (int dx = -1; dx <= 1; ++dx) {
                val[t] = (dy < 0 ? vy0 : (dy > 0 ? vy2 : true)) &&
                         (dx < 0 ? vx0 : (dx > 0 ? vx2 : true));
                off[t] = dy * WW + dx;
                ++t;
            }
    }

    float acc[COC];
#pragma unroll
    for (int j = 0; j < COC; ++j) acc[j] = bias[cog + j];

    const int p0 = y * WW + x;
#pragma unroll
    for (int ci = 0; ci < 4; ++ci) {
        const float* p = (ci < 3) ? (rgb + ((size_t)(b * 3 + ci)) * HW + p0)
                                  : (depth + (size_t)b * HW + p0);
        float v[9];
#pragma unroll
        for (int t = 0; t < 9; ++t)
            v[t] = val[t] ? p[off[t]] : 0.0f;

        const float* wp = w + ((size_t)cog * 4 + ci) * 9;
#pragma unroll
        for (int j = 0; j < COC; ++j) {
            const float* wj = wp + (size_t)j * 4 * 9;
#pragma unroll
            for (int t = 0; t < 9; ++t)
                acc[j] = fmaf(wj[t], v[t], acc[j]);
        }
    }

    bf16* op = out + (size_t)cog * HW + p0;
#pragma unroll
    for (int j = 0; j < COC; ++j)
        op[(size_t)j * HW] = __float2bfloat16(fmaxf(acc[j], 0.0f));
}

// ---------------------------------------------------------------------------
// Direct 3x3 SAME conv, single image, bf16 activations, f32 weights/accum.
// in/out are per-batch buffers [CIN,HW] / [COUT,HW].
// ---------------------------------------------------------------------------
template<int CIN, int COC, bool RELU>
__global__ __launch_bounds__(256) void conv3x3_b(const bf16* __restrict__ in,
                                                 const float* __restrict__ w,
                                                 const float* __restrict__ bias,
                                                 bf16* __restrict__ out)
{
    const int tid = threadIdx.x;
    const int x = blockIdx.x * 64 + (tid & 63);
    const int y = blockIdx.y * 4 + (tid >> 6);
    const int cog = blockIdx.z * COC;

    const bool vy0 = (y > 0), vy2 = (y < HH - 1);
    const bool vx0 = (x > 0), vx2 = (x < WW - 1);
    bool val[9];
    int  off[9];
    {
        int t = 0;
        for (int dy = -1; dy <= 1; ++dy)
            for (int dx = -1; dx <= 1; ++dx) {
                val[t] = (dy < 0 ? vy0 : (dy > 0 ? vy2 : true)) &&
                         (dx < 0 ? vx0 : (dx > 0 ? vx2 : true));
                off[t] = dy * WW + dx;
                ++t;
            }
    }

    float acc[COC];
#pragma unroll
    for (int j = 0; j < COC; ++j) acc[j] = bias[cog + j];

    const int p0 = y * WW + x;
    const bf16* base = in + p0;

    for (int ci = 0; ci < CIN; ++ci) {
        const bf16* p = base + (size_t)ci * HW;
        float v[9];
#pragma unroll
        for (int t = 0; t < 9; ++t)
            v[t] = val[t] ? __bfloat162float(p[off[t]]) : 0.0f;

        const float* wp = w + ((size_t)cog * CIN + ci) * 9;
#pragma unroll
        for (int j = 0; j < COC; ++j) {
            const float* wj = wp + (size_t)j * CIN * 9;
#pragma unroll
            for (int t = 0; t < 9; ++t)
                acc[j] = fmaf(wj[t], v[t], acc[j]);
        }
    }

    bf16* op = out + (size_t)cog * HW + p0;
#pragma unroll
    for (int j = 0; j < COC; ++j) {
        float r = RELU ? fmaxf(acc[j], 0.0f) : acc[j];
        op[(size_t)j * HW] = __float2bfloat16(r);
    }
}

// ---------------------------------------------------------------------------
// Head: 3x3 conv (CIN=64 -> 11) + per-pixel softmax over the 11 channels,
// single image, writing f32 NCHW into outk (the b-th slice of kh/kv output).
// ---------------------------------------------------------------------------
__global__ __launch_bounds__(256) void conv3x3_softmax_b(const bf16* __restrict__ in,
                                                         const float* __restrict__ w,
                                                         const float* __restrict__ bias,
                                                         float* __restrict__ outk)
{
    const int tid = threadIdx.x;
    const int x = blockIdx.x * 64 + (tid & 63);
    const int y = blockIdx.y * 4 + (tid >> 6);
    constexpr int CIN = 64;

    const bool vy0 = (y > 0), vy2 = (y < HH - 1);
    const bool vx0 = (x > 0), vx2 = (x < WW - 1);
    bool val[9];
    int  off[9];
    {
        int t = 0;
        for (int dy = -1; dy <= 1; ++dy)
            for (int dx = -1; dx <= 1; ++dx) {
                val[t] = (dy < 0 ? vy0 : (dy > 0 ? vy2 : true)) &&
                         (dx < 0 ? vx0 : (dx > 0 ? vx2 : true));
                off[t] = dy * WW + dx;
                ++t;
            }
    }

    float acc[11];
#pragma unroll
    for (int j = 0; j < 11; ++j) acc[j] = bias[j];

    const int p0 = y * WW + x;
    const bf16* base = in + p0;

    for (int ci = 0; ci < CIN; ++ci) {
        const bf16* p = base + (size_t)ci * HW;
        float v[9];
#pragma unroll
        for (int t = 0; t < 9; ++t)
            v[t] = val[t] ? __bfloat162float(p[off[t]]) : 0.0f;

        const float* wp = w + (size_t)ci * 9;
#pragma unroll
        for (int j = 0; j < 11; ++j) {
            const float* wj = wp + (size_t)j * CIN * 9;
#pragma unroll
            for (int t = 0; t < 9; ++t)
                acc[j] = fmaf(wj[t], v[t], acc[j]);
        }
    }

    float m = acc[0];
#pragma unroll
    for (int j = 1; j < 11; ++j) m = fmaxf(m, acc[j]);
    float s = 0.0f;
#pragma unroll
    for (int j = 0; j < 11; ++j) { acc[j] = expf(acc[j] - m); s += acc[j]; }
    float inv = 1.0f / s;

    float* op = outk + p0;
#pragma unroll
    for (int j = 0; j < 11; ++j)
        op[(size_t)j * HW] = acc[j] * inv;
}

// ---------------------------------------------------------------------------
// Horizontal separable pass (full batch): h = sum_i kh_i * shift_x(rgb, i-5)
// idx covers B*HW = 2^19 elements; b = idx >> 16 (HW = 2^16).
// ---------------------------------------------------------------------------
__global__ __launch_bounds__(256) void hpass(const float* __restrict__ rgb,
                                             const float* __restrict__ kh,
                                             float* __restrict__ h)
{
    int idx = blockIdx.x * 256 + threadIdx.x;     // b*HW + p, total 524288
    int b = idx >> 16;                            // FIX: HW = 2^16
    int p = idx & (HW - 1);
    int y = p >> 8;
    int x = p & 255;

    float kw[11];
#pragma unroll
    for (int i = 0; i < 11; ++i) kw[i] = kh[((size_t)(b * 11 + i)) * HW + p];

#pragma unroll
    for (int c = 0; c < 3; ++c) {
        const float* rp = rgb + ((size_t)(b * 3 + c)) * HW + (size_t)y * WW;
        float s = 0.0f;
#pragma unroll
        for (int i = 0; i < 11; ++i) {
            int xx = x + i - 5;
            if (xx >= 0 && xx < WW) s = fmaf(kw[i], rp[xx], s);
        }
        h[((size_t)(b * 3 + c)) * HW + p] = s;
    }
}

// ---------------------------------------------------------------------------
// Vertical pass + depth-mask composite. Writes final, blurred, mask.
// ---------------------------------------------------------------------------
__global__ __launch_bounds__(256) void vpass_compose(const float* __restrict__ h,
                                                     const float* __restrict__ kv,
                                                     const float* __restrict__ rgb,
                                                     const float* __restrict__ depth,
                                                     float* __restrict__ fin,
                                                     float* __restrict__ blur,
                                                     float* __restrict__ masko)
{
    int idx = blockIdx.x * 256 + threadIdx.x;
    int b = idx >> 16;                            // FIX: HW = 2^16
    int p = idx & (HW - 1);
    int y = p >> 8;
    int x = p & 255;

    float kw[11];
#pragma unroll
    for (int i = 0; i < 11; ++i) kw[i] = kv[((size_t)(b * 11 + i)) * HW + p];

    float d = depth[idx];
    float mk = (d > 0.2f) ? 1.0f : 0.0f;
    masko[idx] = mk;

#pragma unroll
    for (int c = 0; c < 3; ++c) {
        const float* hp = h + ((size_t)(b * 3 + c)) * HW + x;
        float s = 0.0f;
#pragma unroll
        for (int i = 0; i < 11; ++i) {
            int yy = y + i - 5;
            if (yy >= 0 && yy < HH) s = fmaf(kw[i], hp[(size_t)yy * WW], s);
        }
        size_t o = ((size_t)(b * 3 + c)) * HW + p;
        blur[o] = s;
        fin[o] = mk * rgb[o] + (1.0f - mk) * s;
    }
}

// ---------------------------------------------------------------------------
extern "C" void kernel_launch(void* const* d_in, const int* in_sizes, int n_in,
                              void* d_out, int out_size, void* d_ws, size_t ws_size,
                              hipStream_t stream)
{
    const float* rgb   = (const float*)d_in[0];
    const float* depth = (const float*)d_in[1];
    const float* w1 = (const float*)d_in[2];  const float* b1 = (const float*)d_in[3];
    const float* w2 = (const float*)d_in[4];  const float* b2 = (const float*)d_in[5];
    const float* w3 = (const float*)d_in[6];  const float* b3 = (const float*)d_in[7];
    const float* w4 = (const float*)d_in[8];  const float* b4 = (const float*)d_in[9];
    const float* w5 = (const float*)d_in[10]; const float* b5 = (const float*)d_in[11];
    const float* wh = (const float*)d_in[12]; const float* bh = (const float*)d_in[13];
    const float* wv = (const float*)d_in[14]; const float* bv = (const float*)d_in[15];

    float* out    = (float*)d_out;
    float* fin_o  = out;                    // [8,3,256,256]
    float* blur_o = out + 1572864;          // [8,3,256,256]
    float* kh_o   = out + 3145728;          // [8,11,256,256]
    float* kv_o   = out + 8912896;          // [8,11,256,256]
    float* mask_o = out + 14680064;         // [8,1,256,256]

    // Per-batch workspace regions (48 MiB total):
    //   A (16 MiB): f1 (8 MiB) then f4 (16 MiB)
    //   B (16 MiB): f2 (8 MiB) then f5 (8 MiB)
    //   C (16 MiB): f3 (16 MiB) then full-batch hbuf (6 MiB f32)
    char* ws = (char*)d_ws;
    const size_t MB16 = (size_t)16 * 1024 * 1024;
    bf16* bufA = (bf16*)ws;
    bf16* bufB = (bf16*)(ws + MB16);
    bf16* bufC = (bf16*)(ws + 2 * MB16);
    float* hbuf = (float*)bufC;

    dim3 blk(256);
    dim3 g64(4, 64, 4);     // 64 out-ch, COC=16
    dim3 g128(4, 64, 8);    // 128 out-ch, COC=16
    dim3 gHead(4, 64, 1);

    for (int b = 0; b < BB; ++b) {
        conv3x3_first<16><<<g64, blk, 0, stream>>>(rgb, depth, w1, b1, bufA, b);
        conv3x3_b<64, 16, true><<<g64, blk, 0, stream>>>(bufA, w2, b2, bufB);
        conv3x3_b<64, 16, true><<<g128, blk, 0, stream>>>(bufB, w3, b3, bufC);
        conv3x3_b<128, 16, true><<<g128, blk, 0, stream>>>(bufC, w4, b4, bufA);
        conv3x3_b<128, 16, true><<<g64, blk, 0, stream>>>(bufA, w5, b5, bufB);
        conv3x3_softmax_b<<<gHead, blk, 0, stream>>>(bufB, wh, bh, kh_o + (size_t)b * 11 * HW);
        conv3x3_softmax_b<<<gHead, blk, 0, stream>>>(bufB, wv, bv, kv_o + (size_t)b * 11 * HW);
    }

    // separable blur + composite (full batch; bufC/f3 is dead by now)
    hpass<<<dim3(2048), blk, 0, stream>>>(rgb, kh_o, hbuf);
    vpass_compose<<<dim3(2048), blk, 0, stream>>>(hbuf, kv_o, rgb, depth,
                                                  fin_o, blur_o, mask_o);
}

// Round 4
// 2349.772 us; speedup vs baseline: 5.3627x; 5.3627x over previous
//
#include <hip/hip_runtime.h>
#include <hip/hip_bf16.h>
#include <math.h>

// Problem constants (B=8, H=W=256, K=11 taps, thresh 0.2)
#define HH 256
#define WW 256
#define HW (HH*WW)
#define BB 8

typedef __hip_bfloat16 bf16;
typedef __attribute__((ext_vector_type(8))) short short8;   // 8 bf16 (4 VGPRs)
typedef __attribute__((ext_vector_type(4))) float f32x4;    // MFMA acc

__device__ __forceinline__ float bflo(unsigned u) { return __uint_as_float(u << 16); }
__device__ __forceinline__ float bfhi(unsigned u) { return __uint_as_float(u & 0xffff0000u); }

// ---------------------------------------------------------------------------
// Weight reorder: OIHW f32 -> [t][co][ci] bf16 (t = ky*3+kx)
// ---------------------------------------------------------------------------
template<int CO, int CI>
__global__ __launch_bounds__(256) void reorder_w(const float* __restrict__ w,
                                                 bf16* __restrict__ wr)
{
    int idx = blockIdx.x * 256 + threadIdx.x;
    if (idx >= 9 * CO * CI) return;
    int ci = idx % CI;
    int co = (idx / CI) % CO;
    int t  = idx / (CI * CO);
    wr[idx] = __float2bfloat16(w[((size_t)co * CI + ci) * 9 + t]);
}

// ---------------------------------------------------------------------------
// conv1: 3x3 conv over concat(rgb,depth) [4ch f32, NCHW planar inputs],
// ReLU, output NHWC bf16 [HW][64]. Per-batch. K=36 -> stays direct (1.3% of FLOPs).
// ---------------------------------------------------------------------------
template<int COC>
__global__ __launch_bounds__(256) void conv3x3_first(const float* __restrict__ rgb,
                                                     const float* __restrict__ depth,
                                                     const float* __restrict__ w,
                                                     const float* __restrict__ bias,
                                                     bf16* __restrict__ out, int b)
{
    const int tid = threadIdx.x;
    const int x = blockIdx.x * 64 + (tid & 63);
    const int y = blockIdx.y * 4 + (tid >> 6);
    const int cog = blockIdx.z * COC;

    const bool vy0 = (y > 0), vy2 = (y < HH - 1);
    const bool vx0 = (x > 0), vx2 = (x < WW - 1);
    bool val[9];
    int  off[9];
    {
        int t = 0;
        for (int dy = -1; dy <= 1; ++dy)
            for (int dx = -1; dx <= 1; ++dx) {
                val[t] = (dy < 0 ? vy0 : (dy > 0 ? vy2 : true)) &&
                         (dx < 0 ? vx0 : (dx > 0 ? vx2 : true));
                off[t] = dy * WW + dx;
                ++t;
            }
    }

    float acc[COC];
#pragma unroll
    for (int j = 0; j < COC; ++j) acc[j] = bias[cog + j];

    const int p0 = y * WW + x;
#pragma unroll
    for (int ci = 0; ci < 4; ++ci) {
        const float* p = (ci < 3) ? (rgb + ((size_t)(b * 3 + ci)) * HW + p0)
                                  : (depth + (size_t)b * HW + p0);
        float v[9];
#pragma unroll
        for (int t = 0; t < 9; ++t)
            v[t] = val[t] ? p[off[t]] : 0.0f;

        const float* wp = w + ((size_t)cog * 4 + ci) * 9;
#pragma unroll
        for (int j = 0; j < COC; ++j) {
            const float* wj = wp + (size_t)j * 4 * 9;
#pragma unroll
            for (int t = 0; t < 9; ++t)
                acc[j] = fmaf(wj[t], v[t], acc[j]);
        }
    }

    bf16* op = out + (size_t)p0 * 64 + cog;      // NHWC, 16 contiguous bf16
#pragma unroll
    for (int j = 0; j < COC; ++j)
        op[j] = __float2bfloat16(fmaxf(acc[j], 0.0f));
}

// ---------------------------------------------------------------------------
// MFMA implicit-GEMM 3x3 conv, single image.
// in  : NHWC bf16 [HW][CIN]
// wr  : reordered weights bf16 [9][COUT][CIN]
// out : NHWC bf16 [HW][COUT], ReLU
// Block = 4 waves; wave w handles row y0+w, 64 pixels (4 M-frags of 16),
// 64 output channels (4 N-frags of 16). Per (t,k0): 4 A-loads (16B, global,
// NHWC-contiguous), 4 B-loads (16B, L2-broadcast), 16 MFMAs.
// ---------------------------------------------------------------------------
template<int CIN>
__global__ __launch_bounds__(256) void conv_mfma(const bf16* __restrict__ in,
                                                 const bf16* __restrict__ wr,
                                                 const float* __restrict__ bias,
                                                 bf16* __restrict__ out,
                                                 int COUT)
{
    const int tid  = threadIdx.x;
    const int lane = tid & 63;
    const int wv   = tid >> 6;        // wave id 0..3 -> row within tile
    const int m    = lane & 15;       // A-row / B-col / C-col index
    const int q    = lane >> 4;       // quad -> k-octet / C row group
    const int x0   = blockIdx.x * 64;
    const int y    = blockIdx.y * 4 + wv;
    const int cog  = blockIdx.z * 64;

    f32x4 acc[4][4];
#pragma unroll
    for (int f = 0; f < 4; ++f)
#pragma unroll
        for (int nt = 0; nt < 4; ++nt)
            acc[f][nt] = (f32x4){0.f, 0.f, 0.f, 0.f};

    const short8 zero8 = {0, 0, 0, 0, 0, 0, 0, 0};

#pragma unroll
    for (int t = 0; t < 9; ++t) {
        const int dy = t / 3 - 1, dx = t % 3 - 1;
        const int yy = y + dy;
        if (yy < 0 || yy >= HH) continue;            // wave-uniform branch
        const bf16* wt = wr + (size_t)t * COUT * CIN + (size_t)(cog + m) * CIN + q * 8;
#pragma unroll
        for (int k0 = 0; k0 < CIN; k0 += 32) {
            short8 a[4];
#pragma unroll
            for (int f = 0; f < 4; ++f) {
                const int xx = x0 + f * 16 + m + dx;
                if (xx >= 0 && xx < WW)
                    a[f] = *(const short8*)(in + ((size_t)yy * WW + xx) * CIN + k0 + q * 8);
                else
                    a[f] = zero8;
            }
#pragma unroll
            for (int nt = 0; nt < 4; ++nt) {
                short8 bfr = *(const short8*)(wt + (size_t)nt * 16 * CIN + k0);
#pragma unroll
                for (int f = 0; f < 4; ++f)
                    acc[f][nt] = __builtin_amdgcn_mfma_f32_16x16x32_bf16(a[f], bfr, acc[f][nt], 0, 0, 0);
            }
        }
    }

    // Epilogue. C/D layout: col = lane&15 (=co offset), row = q*4 + reg (=pixel).
#pragma unroll
    for (int nt = 0; nt < 4; ++nt) {
        const int co = cog + nt * 16 + m;
        const float bb = bias[co];
#pragma unroll
        for (int f = 0; f < 4; ++f) {
#pragma unroll
            for (int r = 0; r < 4; ++r) {
                const int xp = x0 + f * 16 + q * 4 + r;
                const float v = fmaxf(acc[f][nt][r] + bb, 0.0f);
                out[((size_t)y * WW + xp) * COUT + co] = __float2bfloat16(v);
            }
        }
    }
}

// ---------------------------------------------------------------------------
// Head: 3x3 conv (NHWC bf16 in [HW][64] -> 11) + per-pixel softmax,
// writing f32 planar [11][HW] into the b-th slice of kh/kv output.
// Input loads: uint4 (8 bf16); weight loads wave-uniform (s_load).
// ---------------------------------------------------------------------------
__global__ __launch_bounds__(256) void head_softmax(const bf16* __restrict__ in,
                                                    const bf16* __restrict__ wr, // [9][11][64]
                                                    const float* __restrict__ bias,
                                                    float* __restrict__ outk)
{
    const int tid = threadIdx.x;
    const int x = blockIdx.x * 64 + (tid & 63);
    const int y = blockIdx.y * 4 + (tid >> 6);
    const int p0 = y * WW + x;

    float acc[11];
#pragma unroll
    for (int j = 0; j < 11; ++j) acc[j] = bias[j];

    for (int t = 0; t < 9; ++t) {
        const int dy = t / 3 - 1, dx = t % 3 - 1;
        const int yy = y + dy, xx = x + dx;
        if (yy < 0 || yy >= HH || xx < 0 || xx >= WW) continue;

        float xin[64];
        const uint4* ip = (const uint4*)(in + ((size_t)yy * WW + xx) * 64);
#pragma unroll
        for (int oc = 0; oc < 8; ++oc) {
            uint4 u = ip[oc];
            xin[oc * 8 + 0] = bflo(u.x); xin[oc * 8 + 1] = bfhi(u.x);
            xin[oc * 8 + 2] = bflo(u.y); xin[oc * 8 + 3] = bfhi(u.y);
            xin[oc * 8 + 4] = bflo(u.z); xin[oc * 8 + 5] = bfhi(u.z);
            xin[oc * 8 + 6] = bflo(u.w); xin[oc * 8 + 7] = bfhi(u.w);
        }

        const uint4* wp = (const uint4*)(wr + (size_t)t * 11 * 64);
#pragma unroll
        for (int j = 0; j < 11; ++j) {
#pragma unroll
            for (int oc = 0; oc < 8; ++oc) {
                uint4 u = wp[j * 8 + oc];
                acc[j] = fmaf(bflo(u.x), xin[oc * 8 + 0], acc[j]);
                acc[j] = fmaf(bfhi(u.x), xin[oc * 8 + 1], acc[j]);
                acc[j] = fmaf(bflo(u.y), xin[oc * 8 + 2], acc[j]);
                acc[j] = fmaf(bfhi(u.y), xin[oc * 8 + 3], acc[j]);
                acc[j] = fmaf(bflo(u.z), xin[oc * 8 + 4], acc[j]);
                acc[j] = fmaf(bfhi(u.z), xin[oc * 8 + 5], acc[j]);
                acc[j] = fmaf(bflo(u.w), xin[oc * 8 + 6], acc[j]);
                acc[j] = fmaf(bfhi(u.w), xin[oc * 8 + 7], acc[j]);
            }
        }
    }

    float mx = acc[0];
#pragma unroll
    for (int j = 1; j < 11; ++j) mx = fmaxf(mx, acc[j]);
    float s = 0.0f;
#pragma unroll
    for (int j = 0; j < 11; ++j) { acc[j] = expf(acc[j] - mx); s += acc[j]; }
    const float inv = 1.0f / s;

    float* op = outk + p0;
#pragma unroll
    for (int j = 0; j < 11; ++j)
        op[(size_t)j * HW] = acc[j] * inv;
}

// ---------------------------------------------------------------------------
// Horizontal separable pass (full batch): h = sum_i kh_i * shift_x(rgb, i-5)
// ---------------------------------------------------------------------------
__global__ __launch_bounds__(256) void hpass(const float* __restrict__ rgb,
                                             const float* __restrict__ kh,
                                             float* __restrict__ h)
{
    int idx = blockIdx.x * 256 + threadIdx.x;     // b*HW + p, total 524288
    int b = idx >> 16;                            // HW = 2^16
    int p = idx & (HW - 1);
    int y = p >> 8;
    int x = p & 255;

    float kw[11];
#pragma unroll
    for (int i = 0; i < 11; ++i) kw[i] = kh[((size_t)(b * 11 + i)) * HW + p];

#pragma unroll
    for (int c = 0; c < 3; ++c) {
        const float* rp = rgb + ((size_t)(b * 3 + c)) * HW + (size_t)y * WW;
        float s = 0.0f;
#pragma unroll
        for (int i = 0; i < 11; ++i) {
            int xx = x + i - 5;
            if (xx >= 0 && xx < WW) s = fmaf(kw[i], rp[xx], s);
        }
        h[((size_t)(b * 3 + c)) * HW + p] = s;
    }
}

// ---------------------------------------------------------------------------
// Vertical pass + depth-mask composite. Writes final, blurred, mask.
// ---------------------------------------------------------------------------
__global__ __launch_bounds__(256) void vpass_compose(const float* __restrict__ h,
                                                     const float* __restrict__ kv,
                                                     const float* __restrict__ rgb,
                                                     const float* __restrict__ depth,
                                                     float* __restrict__ fin,
                                                     float* __restrict__ blur,
                                                     float* __restrict__ masko)
{
    int idx = blockIdx.x * 256 + threadIdx.x;
    int b = idx >> 16;                            // HW = 2^16
    int p = idx & (HW - 1);
    int y = p >> 8;
    int x = p & 255;

    float kw[11];
#pragma unroll
    for (int i = 0; i < 11; ++i) kw[i] = kv[((size_t)(b * 11 + i)) * HW + p];

    float d = depth[idx];
    float mk = (d > 0.2f) ? 1.0f : 0.0f;
    masko[idx] = mk;

#pragma unroll
    for (int c = 0; c < 3; ++c) {
        const float* hp = h + ((size_t)(b * 3 + c)) * HW + x;
        float s = 0.0f;
#pragma unroll
        for (int i = 0; i < 11; ++i) {
            int yy = y + i - 5;
            if (yy >= 0 && yy < HH) s = fmaf(kw[i], hp[(size_t)yy * WW], s);
        }
        size_t o = ((size_t)(b * 3 + c)) * HW + p;
        blur[o] = s;
        fin[o] = mk * rgb[o] + (1.0f - mk) * s;
    }
}

// ---------------------------------------------------------------------------
extern "C" void kernel_launch(void* const* d_in, const int* in_sizes, int n_in,
                              void* d_out, int out_size, void* d_ws, size_t ws_size,
                              hipStream_t stream)
{
    const float* rgb   = (const float*)d_in[0];
    const float* depth = (const float*)d_in[1];
    const float* w1 = (const float*)d_in[2];  const float* b1 = (const float*)d_in[3];
    const float* w2 = (const float*)d_in[4];  const float* b2 = (const float*)d_in[5];
    const float* w3 = (const float*)d_in[6];  const float* b3 = (const float*)d_in[7];
    const float* w4 = (const float*)d_in[8];  const float* b4 = (const float*)d_in[9];
    const float* w5 = (const float*)d_in[10]; const float* b5 = (const float*)d_in[11];
    const float* wh = (const float*)d_in[12]; const float* bh = (const float*)d_in[13];
    const float* wv = (const float*)d_in[14]; const float* bv = (const float*)d_in[15];

    float* out    = (float*)d_out;
    float* fin_o  = out;                    // [8,3,256,256]
    float* blur_o = out + 1572864;          // [8,3,256,256]
    float* kh_o   = out + 3145728;          // [8,11,256,256]
    float* kv_o   = out + 8912896;          // [8,11,256,256]
    float* mask_o = out + 14680064;         // [8,1,256,256]

    // Workspace (49 MiB):
    //   A (16 MiB): f1 [HW][64] then f4 [HW][128]
    //   B (16 MiB): f2 [HW][64] then f5 [HW][64]
    //   C (16 MiB): f3 [HW][128]; reused as full-batch hbuf (6 MiB f32)
    //   W (~1 MiB): reordered bf16 weights [t][co][ci]
    char* ws = (char*)d_ws;
    const size_t MB16 = (size_t)16 * 1024 * 1024;
    bf16* bufA = (bf16*)ws;
    bf16* bufB = (bf16*)(ws + MB16);
    bf16* bufC = (bf16*)(ws + 2 * MB16);
    float* hbuf = (float*)bufC;

    bf16* w2r = (bf16*)(ws + 3 * MB16);
    bf16* w3r = w2r + 9 * 64 * 64;
    bf16* w4r = w3r + 9 * 128 * 64;
    bf16* w5r = w4r + 9 * 128 * 128;
    bf16* whr = w5r + 9 * 64 * 128;
    bf16* wvr = whr + 9 * 11 * 64;

    dim3 blk(256);

    // one-time weight reorders (graph-safe: identical work every call)
    reorder_w<64, 64>  <<<dim3((9*64*64   + 255) / 256), blk, 0, stream>>>(w2, w2r);
    reorder_w<128, 64> <<<dim3((9*128*64  + 255) / 256), blk, 0, stream>>>(w3, w3r);
    reorder_w<128, 128><<<dim3((9*128*128 + 255) / 256), blk, 0, stream>>>(w4, w4r);
    reorder_w<64, 128> <<<dim3((9*64*128  + 255) / 256), blk, 0, stream>>>(w5, w5r);
    reorder_w<11, 64>  <<<dim3((9*11*64   + 255) / 256), blk, 0, stream>>>(wh, whr);
    reorder_w<11, 64>  <<<dim3((9*11*64   + 255) / 256), blk, 0, stream>>>(wv, wvr);

    for (int b = 0; b < BB; ++b) {
        conv3x3_first<16><<<dim3(4, 64, 4), blk, 0, stream>>>(rgb, depth, w1, b1, bufA, b);
        conv_mfma<64> <<<dim3(4, 64, 1), blk, 0, stream>>>(bufA, w2r, b2, bufB, 64);
        conv_mfma<64> <<<dim3(4, 64, 2), blk, 0, stream>>>(bufB, w3r, b3, bufC, 128);
        conv_mfma<128><<<dim3(4, 64, 2), blk, 0, stream>>>(bufC, w4r, b4, bufA, 128);
        conv_mfma<128><<<dim3(4, 64, 1), blk, 0, stream>>>(bufA, w5r, b5, bufB, 64);
        head_softmax<<<dim3(4, 64), blk, 0, stream>>>(bufB, whr, bh, kh_o + (size_t)b * 11 * HW);
        head_softmax<<<dim3(4, 64), blk, 0, stream>>>(bufB, wvr, bv, kv_o + (size_t)b * 11 * HW);
    }

    // separable blur + composite (full batch; bufC/f3 dead by now)
    hpass<<<dim3(2048), blk, 0, stream>>>(rgb, kh_o, hbuf);
    vpass_compose<<<dim3(2048), blk, 0, stream>>>(hbuf, kv_o, rgb, depth,
                                                  fin_o, blur_o, mask_o);
}

// Round 5
// 1744.916 us; speedup vs baseline: 7.2216x; 1.3466x over previous
//
#include <hip/hip_runtime.h>
#include <hip/hip_bf16.h>
#include <math.h>

// Problem constants (B=8, H=W=256, K=11 taps, thresh 0.2)
#define HH 256
#define WW 256
#define HW (HH*WW)
#define BB 8

typedef __hip_bfloat16 bf16;
typedef __attribute__((ext_vector_type(8))) short short8;   // 8 bf16 (4 VGPRs)
typedef __attribute__((ext_vector_type(4))) float f32x4;    // MFMA acc

__device__ __forceinline__ float bflo(unsigned u) { return __uint_as_float(u << 16); }
__device__ __forceinline__ float bfhi(unsigned u) { return __uint_as_float(u & 0xffff0000u); }

// ---------------------------------------------------------------------------
// Weight reorder: OIHW f32 -> [t][co][ci] bf16 (t = ky*3+kx)
// ---------------------------------------------------------------------------
template<int CO, int CI>
__global__ __launch_bounds__(256) void reorder_w(const float* __restrict__ w,
                                                 bf16* __restrict__ wr)
{
    int idx = blockIdx.x * 256 + threadIdx.x;
    if (idx >= 9 * CO * CI) return;
    int ci = idx % CI;
    int co = (idx / CI) % CO;
    int t  = idx / (CI * CO);
    wr[idx] = __float2bfloat16(w[((size_t)co * CI + ci) * 9 + t]);
}

// ---------------------------------------------------------------------------
// conv1: 3x3 conv over concat(rgb,depth) [4ch f32, NCHW planar inputs],
// ReLU, output NHWC bf16 [G][HW][64]. Batched: blockIdx.y = img*64 + ytile.
// ---------------------------------------------------------------------------
template<int COC>
__global__ __launch_bounds__(256) void conv3x3_first(const float* __restrict__ rgb,
                                                     const float* __restrict__ depth,
                                                     const float* __restrict__ w,
                                                     const float* __restrict__ bias,
                                                     bf16* __restrict__ out, int b0)
{
    const int tid = threadIdx.x;
    const int img = blockIdx.y >> 6;
    const int b   = b0 + img;
    const int x = blockIdx.x * 64 + (tid & 63);
    const int y = (blockIdx.y & 63) * 4 + (tid >> 6);
    const int cog = blockIdx.z * COC;

    const bool vy0 = (y > 0), vy2 = (y < HH - 1);
    const bool vx0 = (x > 0), vx2 = (x < WW - 1);
    bool val[9];
    int  off[9];
    {
        int t = 0;
        for (int dy = -1; dy <= 1; ++dy)
            for (int dx = -1; dx <= 1; ++dx) {
                val[t] = (dy < 0 ? vy0 : (dy > 0 ? vy2 : true)) &&
                         (dx < 0 ? vx0 : (dx > 0 ? vx2 : true));
                off[t] = dy * WW + dx;
                ++t;
            }
    }

    float acc[COC];
#pragma unroll
    for (int j = 0; j < COC; ++j) acc[j] = bias[cog + j];

    const int p0 = y * WW + x;
#pragma unroll
    for (int ci = 0; ci < 4; ++ci) {
        const float* p = (ci < 3) ? (rgb + ((size_t)(b * 3 + ci)) * HW + p0)
                                  : (depth + (size_t)b * HW + p0);
        float v[9];
#pragma unroll
        for (int t = 0; t < 9; ++t)
            v[t] = val[t] ? p[off[t]] : 0.0f;

        const float* wp = w + ((size_t)cog * 4 + ci) * 9;
#pragma unroll
        for (int j = 0; j < COC; ++j) {
            const float* wj = wp + (size_t)j * 4 * 9;
#pragma unroll
            for (int t = 0; t < 9; ++t)
                acc[j] = fmaf(wj[t], v[t], acc[j]);
        }
    }

    bf16* op = out + (size_t)img * HW * 64 + (size_t)p0 * 64 + cog;
#pragma unroll
    for (int j = 0; j < COC; ++j)
        op[j] = __float2bfloat16(fmaxf(acc[j], 0.0f));
}

// ---------------------------------------------------------------------------
// MFMA implicit-GEMM 3x3 conv, batched over G images.
// in  : NHWC bf16 [G][HW][CIN]     wr : bf16 [9][COUT][CIN]
// out : NHWC bf16 [G][HW][COUT], ReLU
// blockIdx.y = img*64 + ytile. Wave = 64 px x 64 couts (16 MFMA frags).
// ---------------------------------------------------------------------------
template<int CIN>
__global__ __launch_bounds__(256) void conv_mfma(const bf16* __restrict__ in,
                                                 const bf16* __restrict__ wr,
                                                 const float* __restrict__ bias,
                                                 bf16* __restrict__ out,
                                                 int COUT)
{
    const int tid  = threadIdx.x;
    const int lane = tid & 63;
    const int wv   = tid >> 6;
    const int m    = lane & 15;
    const int q    = lane >> 4;
    const int img  = blockIdx.y >> 6;
    const int x0   = blockIdx.x * 64;
    const int y    = (blockIdx.y & 63) * 4 + wv;
    const int cog  = blockIdx.z * 64;

    const bf16* in_i  = in  + (size_t)img * HW * CIN;
    bf16*       out_i = out + (size_t)img * HW * COUT;

    f32x4 acc[4][4];
#pragma unroll
    for (int f = 0; f < 4; ++f)
#pragma unroll
        for (int nt = 0; nt < 4; ++nt)
            acc[f][nt] = (f32x4){0.f, 0.f, 0.f, 0.f};

    const short8 zero8 = {0, 0, 0, 0, 0, 0, 0, 0};

#pragma unroll
    for (int t = 0; t < 9; ++t) {
        const int dy = t / 3 - 1, dx = t % 3 - 1;
        const int yy = y + dy;
        if (yy < 0 || yy >= HH) continue;            // wave-uniform branch
        const bf16* wt = wr + (size_t)t * COUT * CIN + (size_t)(cog + m) * CIN + q * 8;
#pragma unroll
        for (int k0 = 0; k0 < CIN; k0 += 32) {
            short8 a[4];
#pragma unroll
            for (int f = 0; f < 4; ++f) {
                const int xx = x0 + f * 16 + m + dx;
                if (xx >= 0 && xx < WW)
                    a[f] = *(const short8*)(in_i + ((size_t)yy * WW + xx) * CIN + k0 + q * 8);
                else
                    a[f] = zero8;
            }
#pragma unroll
            for (int nt = 0; nt < 4; ++nt) {
                short8 bfr = *(const short8*)(wt + (size_t)nt * 16 * CIN + k0);
#pragma unroll
                for (int f = 0; f < 4; ++f)
                    acc[f][nt] = __builtin_amdgcn_mfma_f32_16x16x32_bf16(a[f], bfr, acc[f][nt], 0, 0, 0);
            }
        }
    }

    // Epilogue. C/D layout: col = lane&15 (=co offset), row = q*4 + reg (=pixel).
#pragma unroll
    for (int nt = 0; nt < 4; ++nt) {
        const int co = cog + nt * 16 + m;
        const float bb = bias[co];
#pragma unroll
        for (int f = 0; f < 4; ++f) {
#pragma unroll
            for (int r = 0; r < 4; ++r) {
                const int xp = x0 + f * 16 + q * 4 + r;
                const float v = fmaxf(acc[f][nt][r] + bb, 0.0f);
                out_i[((size_t)y * WW + xp) * COUT + co] = __float2bfloat16(v);
            }
        }
    }
}

// ---------------------------------------------------------------------------
// Head: 3x3 conv (NHWC bf16 [G][HW][64] -> 11) + per-pixel softmax,
// writing f32 planar [11][HW] into the (b0+img)-th slice of kh/kv output.
// ---------------------------------------------------------------------------
__global__ __launch_bounds__(256) void head_softmax(const bf16* __restrict__ in,
                                                    const bf16* __restrict__ wr, // [9][11][64]
                                                    const float* __restrict__ bias,
                                                    float* __restrict__ outk_base,
                                                    int b0)
{
    const int tid = threadIdx.x;
    const int img = blockIdx.y >> 6;
    const int x = blockIdx.x * 64 + (tid & 63);
    const int y = (blockIdx.y & 63) * 4 + (tid >> 6);
    const int p0 = y * WW + x;

    const bf16* in_i = in + (size_t)img * HW * 64;
    float* outk = outk_base + (size_t)(b0 + img) * 11 * HW;

    float acc[11];
#pragma unroll
    for (int j = 0; j < 11; ++j) acc[j] = bias[j];

    for (int t = 0; t < 9; ++t) {
        const int dy = t / 3 - 1, dx = t % 3 - 1;
        const int yy = y + dy, xx = x + dx;
        if (yy < 0 || yy >= HH || xx < 0 || xx >= WW) continue;

        float xin[64];
        const uint4* ip = (const uint4*)(in_i + ((size_t)yy * WW + xx) * 64);
#pragma unroll
        for (int oc = 0; oc < 8; ++oc) {
            uint4 u = ip[oc];
            xin[oc * 8 + 0] = bflo(u.x); xin[oc * 8 + 1] = bfhi(u.x);
            xin[oc * 8 + 2] = bflo(u.y); xin[oc * 8 + 3] = bfhi(u.y);
            xin[oc * 8 + 4] = bflo(u.z); xin[oc * 8 + 5] = bfhi(u.z);
            xin[oc * 8 + 6] = bflo(u.w); xin[oc * 8 + 7] = bfhi(u.w);
        }

        const uint4* wp = (const uint4*)(wr + (size_t)t * 11 * 64);
#pragma unroll
        for (int j = 0; j < 11; ++j) {
#pragma unroll
            for (int oc = 0; oc < 8; ++oc) {
                uint4 u = wp[j * 8 + oc];
                acc[j] = fmaf(bflo(u.x), xin[oc * 8 + 0], acc[j]);
                acc[j] = fmaf(bfhi(u.x), xin[oc * 8 + 1], acc[j]);
                acc[j] = fmaf(bflo(u.y), xin[oc * 8 + 2], acc[j]);
                acc[j] = fmaf(bfhi(u.y), xin[oc * 8 + 3], acc[j]);
                acc[j] = fmaf(bflo(u.z), xin[oc * 8 + 4], acc[j]);
                acc[j] = fmaf(bfhi(u.z), xin[oc * 8 + 5], acc[j]);
                acc[j] = fmaf(bflo(u.w), xin[oc * 8 + 6], acc[j]);
                acc[j] = fmaf(bfhi(u.w), xin[oc * 8 + 7], acc[j]);
            }
        }
    }

    float mx = acc[0];
#pragma unroll
    for (int j = 1; j < 11; ++j) mx = fmaxf(mx, acc[j]);
    float s = 0.0f;
#pragma unroll
    for (int j = 0; j < 11; ++j) { acc[j] = expf(acc[j] - mx); s += acc[j]; }
    const float inv = 1.0f / s;

    float* op = outk + p0;
#pragma unroll
    for (int j = 0; j < 11; ++j)
        op[(size_t)j * HW] = acc[j] * inv;
}

// ---------------------------------------------------------------------------
// Horizontal separable pass (full batch): h = sum_i kh_i * shift_x(rgb, i-5)
// ---------------------------------------------------------------------------
__global__ __launch_bounds__(256) void hpass(const float* __restrict__ rgb,
                                             const float* __restrict__ kh,
                                             float* __restrict__ h)
{
    int idx = blockIdx.x * 256 + threadIdx.x;     // b*HW + p, total 524288
    int b = idx >> 16;                            // HW = 2^16
    int p = idx & (HW - 1);
    int y = p >> 8;
    int x = p & 255;

    float kw[11];
#pragma unroll
    for (int i = 0; i < 11; ++i) kw[i] = kh[((size_t)(b * 11 + i)) * HW + p];

#pragma unroll
    for (int c = 0; c < 3; ++c) {
        const float* rp = rgb + ((size_t)(b * 3 + c)) * HW + (size_t)y * WW;
        float s = 0.0f;
#pragma unroll
        for (int i = 0; i < 11; ++i) {
            int xx = x + i - 5;
            if (xx >= 0 && xx < WW) s = fmaf(kw[i], rp[xx], s);
        }
        h[((size_t)(b * 3 + c)) * HW + p] = s;
    }
}

// ---------------------------------------------------------------------------
// Vertical pass + depth-mask composite. Writes final, blurred, mask.
// ---------------------------------------------------------------------------
__global__ __launch_bounds__(256) void vpass_compose(const float* __restrict__ h,
                                                     const float* __restrict__ kv,
                                                     const float* __restrict__ rgb,
                                                     const float* __restrict__ depth,
                                                     float* __restrict__ fin,
                                                     float* __restrict__ blur,
                                                     float* __restrict__ masko)
{
    int idx = blockIdx.x * 256 + threadIdx.x;
    int b = idx >> 16;                            // HW = 2^16
    int p = idx & (HW - 1);
    int y = p >> 8;
    int x = p & 255;

    float kw[11];
#pragma unroll
    for (int i = 0; i < 11; ++i) kw[i] = kv[((size_t)(b * 11 + i)) * HW + p];

    float d = depth[idx];
    float mk = (d > 0.2f) ? 1.0f : 0.0f;
    masko[idx] = mk;

#pragma unroll
    for (int c = 0; c < 3; ++c) {
        const float* hp = h + ((size_t)(b * 3 + c)) * HW + x;
        float s = 0.0f;
#pragma unroll
        for (int i = 0; i < 11; ++i) {
            int yy = y + i - 5;
            if (yy >= 0 && yy < HH) s = fmaf(kw[i], hp[(size_t)yy * WW], s);
        }
        size_t o = ((size_t)(b * 3 + c)) * HW + p;
        blur[o] = s;
        fin[o] = mk * rgb[o] + (1.0f - mk) * s;
    }
}

// ---------------------------------------------------------------------------
extern "C" void kernel_launch(void* const* d_in, const int* in_sizes, int n_in,
                              void* d_out, int out_size, void* d_ws, size_t ws_size,
                              hipStream_t stream)
{
    const float* rgb   = (const float*)d_in[0];
    const float* depth = (const float*)d_in[1];
    const float* w1 = (const float*)d_in[2];  const float* b1 = (const float*)d_in[3];
    const float* w2 = (const float*)d_in[4];  const float* b2 = (const float*)d_in[5];
    const float* w3 = (const float*)d_in[6];  const float* b3 = (const float*)d_in[7];
    const float* w4 = (const float*)d_in[8];  const float* b4 = (const float*)d_in[9];
    const float* w5 = (const float*)d_in[10]; const float* b5 = (const float*)d_in[11];
    const float* wh = (const float*)d_in[12]; const float* bh = (const float*)d_in[13];
    const float* wv = (const float*)d_in[14]; const float* bv = (const float*)d_in[15];

    float* out    = (float*)d_out;
    float* fin_o  = out;                    // [8,3,256,256]
    float* blur_o = out + 1572864;          // [8,3,256,256]
    float* kh_o   = out + 3145728;          // [8,11,256,256]
    float* kv_o   = out + 8912896;          // [8,11,256,256]
    float* mask_o = out + 14680064;         // [8,1,256,256]

    // --- Select batch group size G from ws_size (deterministic -> graph-safe).
    // Per group: A = G*HW*128*2 (f1 then f4), B = G*HW*64*2 (f2 then f5),
    //            C = G*HW*128*2 (f3; later full-batch hbuf 6.3 MB) ; + 1 MiB weights.
    const size_t perG = (size_t)HW * 2 * (128 + 64 + 128);   // 41.9 MB per image
    const size_t wsz  = (size_t)1 * 1024 * 1024;
    int G = 1;
    if (ws_size >= 8 * perG + wsz) G = 8;
    else if (ws_size >= 4 * perG + wsz) G = 4;
    else if (ws_size >= 2 * perG + wsz) G = 2;

    char* ws = (char*)d_ws;
    const size_t szA = (size_t)G * HW * 128 * 2;
    const size_t szB = (size_t)G * HW * 64 * 2;
    const size_t szC = (size_t)G * HW * 128 * 2;
    bf16* bufA = (bf16*)ws;
    bf16* bufB = (bf16*)(ws + szA);
    bf16* bufC = (bf16*)(ws + szA + szB);
    float* hbuf = (float*)bufC;              // 6.3 MB <= szC (>=16.8 MB)

    bf16* w2r = (bf16*)(ws + szA + szB + szC);
    bf16* w3r = w2r + 9 * 64 * 64;
    bf16* w4r = w3r + 9 * 128 * 64;
    bf16* w5r = w4r + 9 * 128 * 128;
    bf16* whr = w5r + 9 * 64 * 128;
    bf16* wvr = whr + 9 * 11 * 64;

    dim3 blk(256);

    // one-time weight reorders (graph-safe: identical work every call)
    reorder_w<64, 64>  <<<dim3((9*64*64   + 255) / 256), blk, 0, stream>>>(w2, w2r);
    reorder_w<128, 64> <<<dim3((9*128*64  + 255) / 256), blk, 0, stream>>>(w3, w3r);
    reorder_w<128, 128><<<dim3((9*128*128 + 255) / 256), blk, 0, stream>>>(w4, w4r);
    reorder_w<64, 128> <<<dim3((9*64*128  + 255) / 256), blk, 0, stream>>>(w5, w5r);
    reorder_w<11, 64>  <<<dim3((9*11*64   + 255) / 256), blk, 0, stream>>>(wh, whr);
    reorder_w<11, 64>  <<<dim3((9*11*64   + 255) / 256), blk, 0, stream>>>(wv, wvr);

    const int GY = 64 * G;
    for (int b0 = 0; b0 < BB; b0 += G) {
        conv3x3_first<16><<<dim3(4, GY, 4), blk, 0, stream>>>(rgb, depth, w1, b1, bufA, b0);
        conv_mfma<64> <<<dim3(4, GY, 1), blk, 0, stream>>>(bufA, w2r, b2, bufB, 64);
        conv_mfma<64> <<<dim3(4, GY, 2), blk, 0, stream>>>(bufB, w3r, b3, bufC, 128);
        conv_mfma<128><<<dim3(4, GY, 2), blk, 0, stream>>>(bufC, w4r, b4, bufA, 128);
        conv_mfma<128><<<dim3(4, GY, 1), blk, 0, stream>>>(bufA, w5r, b5, bufB, 64);
        head_softmax<<<dim3(4, GY), blk, 0, stream>>>(bufB, whr, bh, kh_o, b0);
        head_softmax<<<dim3(4, GY), blk, 0, stream>>>(bufB, wvr, bv, kv_o, b0);
    }

    // separable blur + composite (full batch; bufC/f3 dead by now)
    hpass<<<dim3(2048), blk, 0, stream>>>(rgb, kh_o, hbuf);
    vpass_compose<<<dim3(2048), blk, 0, stream>>>(hbuf, kv_o, rgb, depth,
                                                  fin_o, blur_o, mask_o);
}

// Round 6
// 1225.525 us; speedup vs baseline: 10.2822x; 1.4238x over previous
//
#include <hip/hip_runtime.h>
#include <hip/hip_bf16.h>
#include <math.h>

// Problem constants (B=8, H=W=256, K=11 taps, thresh 0.2)
#define HH 256
#define WW 256
#define HW (HH*WW)
#define BB 8

typedef __hip_bfloat16 bf16;
typedef __attribute__((ext_vector_type(8))) short short8;   // 8 bf16 (4 VGPRs)
typedef __attribute__((ext_vector_type(4))) float f32x4;    // MFMA acc

__device__ __forceinline__ float bflo(unsigned u) { return __uint_as_float(u << 16); }
__device__ __forceinline__ float bfhi(unsigned u) { return __uint_as_float(u & 0xffff0000u); }

// ---------------------------------------------------------------------------
// Weight reorder: OIHW f32 -> [t][co][ci] bf16 (t = ky*3+kx)
// ---------------------------------------------------------------------------
template<int CO, int CI>
__global__ __launch_bounds__(256) void reorder_w(const float* __restrict__ w,
                                                 bf16* __restrict__ wr)
{
    int idx = blockIdx.x * 256 + threadIdx.x;
    if (idx >= 9 * CO * CI) return;
    int ci = idx % CI;
    int co = (idx / CI) % CO;
    int t  = idx / (CI * CO);
    wr[idx] = __float2bfloat16(w[((size_t)co * CI + ci) * 9 + t]);
}

// Head weights: [11][64][3][3] f32 -> [t][16][64] bf16, co 11..15 zero-padded.
__global__ __launch_bounds__(256) void reorder_w_head(const float* __restrict__ w,
                                                      bf16* __restrict__ wr)
{
    int idx = blockIdx.x * 256 + threadIdx.x;
    if (idx >= 9 * 16 * 64) return;
    int ci = idx % 64;
    int co = (idx / 64) % 16;
    int t  = idx / (64 * 16);
    float v = (co < 11) ? w[((size_t)co * 64 + ci) * 9 + t] : 0.0f;
    wr[idx] = __float2bfloat16(v);
}

// ---------------------------------------------------------------------------
// conv1: 3x3 conv over concat(rgb,depth) [4ch f32 planar], ReLU,
// output NHWC bf16 [G][HW][64]. blockIdx.y = img*64 + ytile.
// ---------------------------------------------------------------------------
template<int COC>
__global__ __launch_bounds__(256) void conv3x3_first(const float* __restrict__ rgb,
                                                     const float* __restrict__ depth,
                                                     const float* __restrict__ w,
                                                     const float* __restrict__ bias,
                                                     bf16* __restrict__ out, int b0)
{
    const int tid = threadIdx.x;
    const int img = blockIdx.y >> 6;
    const int b   = b0 + img;
    const int x = blockIdx.x * 64 + (tid & 63);
    const int y = (blockIdx.y & 63) * 4 + (tid >> 6);
    const int cog = blockIdx.z * COC;

    const bool vy0 = (y > 0), vy2 = (y < HH - 1);
    const bool vx0 = (x > 0), vx2 = (x < WW - 1);
    bool val[9];
    int  off[9];
    {
        int t = 0;
        for (int dy = -1; dy <= 1; ++dy)
            for (int dx = -1; dx <= 1; ++dx) {
                val[t] = (dy < 0 ? vy0 : (dy > 0 ? vy2 : true)) &&
                         (dx < 0 ? vx0 : (dx > 0 ? vx2 : true));
                off[t] = dy * WW + dx;
                ++t;
            }
    }

    float acc[COC];
#pragma unroll
    for (int j = 0; j < COC; ++j) acc[j] = bias[cog + j];

    const int p0 = y * WW + x;
#pragma unroll
    for (int ci = 0; ci < 4; ++ci) {
        const float* p = (ci < 3) ? (rgb + ((size_t)(b * 3 + ci)) * HW + p0)
                                  : (depth + (size_t)b * HW + p0);
        float v[9];
#pragma unroll
        for (int t = 0; t < 9; ++t)
            v[t] = val[t] ? p[off[t]] : 0.0f;

        const float* wp = w + ((size_t)cog * 4 + ci) * 9;
#pragma unroll
        for (int j = 0; j < COC; ++j) {
            const float* wj = wp + (size_t)j * 4 * 9;
#pragma unroll
            for (int t = 0; t < 9; ++t)
                acc[j] = fmaf(wj[t], v[t], acc[j]);
        }
    }

    bf16* op = out + (size_t)img * HW * 64 + (size_t)p0 * 64 + cog;
#pragma unroll
    for (int j = 0; j < COC; ++j)
        op[j] = __float2bfloat16(fmaxf(acc[j], 0.0f));
}

// ---------------------------------------------------------------------------
// LDS-staged MFMA implicit-GEMM 3x3 conv, batched over G images.
// in : NHWC bf16 [G][HW][CIN]   wr : bf16 [9][COUT][CIN]   out : [G][HW][COUT]
// Block = 4 waves = 64px x 4rows x 64co. Per 32-ch K-chunk: stage rows
// y0-1..y0+4 x 66px x 32ch into LDS (halo zeroed -> tap loop is branch-free),
// then 9 taps x 16 MFMA per wave with A from conflict-free ds_read_b128 and
// B prefetched from L2 (no barriers between taps).
// ---------------------------------------------------------------------------
template<int CIN>
__global__ __launch_bounds__(256, 4) void conv_mfma_lds(const bf16* __restrict__ in,
                                                        const bf16* __restrict__ wr,
                                                        const float* __restrict__ bias,
                                                        bf16* __restrict__ out,
                                                        int COUT)
{
    __shared__ bf16 slab[6 * 66 * 32];     // 25344 B

    const int tid  = threadIdx.x;
    const int lane = tid & 63;
    const int wv   = tid >> 6;
    const int m    = lane & 15;
    const int q    = lane >> 4;
    const int img  = blockIdx.y >> 6;
    const int x0   = blockIdx.x * 64;
    const int y0   = (blockIdx.y & 63) * 4;
    const int y    = y0 + wv;
    const int cog  = blockIdx.z * 64;

    const bf16* in_i  = in  + (size_t)img * HW * CIN;
    bf16*       out_i = out + (size_t)img * HW * COUT;

    f32x4 acc[4][4];
#pragma unroll
    for (int f = 0; f < 4; ++f)
#pragma unroll
        for (int nt = 0; nt < 4; ++nt)
            acc[f][nt] = (f32x4){0.f, 0.f, 0.f, 0.f};

    const short8 zero8 = {0, 0, 0, 0, 0, 0, 0, 0};

    for (int k0 = 0; k0 < CIN; k0 += 32) {
        __syncthreads();                   // previous chunk's readers done
        // stage [6 rows][66 px][32 ch]: 1584 16B chunks over 256 threads
        for (int e = tid; e < 1584; e += 256) {
            const int row = e / 264;       // 264 = 66*4
            const int rem = e - row * 264;
            const int px  = rem >> 2;
            const int seg = rem & 3;
            const int yy  = y0 - 1 + row;
            const int xx  = x0 - 1 + px;
            short8 v = zero8;
            if (yy >= 0 && yy < HH && xx >= 0 && xx < WW)
                v = *(const short8*)(in_i + ((size_t)yy * WW + xx) * CIN + k0 + seg * 8);
            *(short8*)(&slab[(row * 66 + px) * 32 + seg * 8]) = v;
        }
        __syncthreads();

#pragma unroll
        for (int t = 0; t < 9; ++t) {
            const int dy = t / 3 - 1, dx = t % 3 - 1;
            const int row = wv + dy + 1;   // 0..5
            short8 a[4];
#pragma unroll
            for (int f = 0; f < 4; ++f)
                a[f] = *(const short8*)(&slab[(row * 66 + (f * 16 + m + dx + 1)) * 32 + q * 8]);
            const bf16* wt = wr + (size_t)t * COUT * CIN + (size_t)(cog + m) * CIN + k0 + q * 8;
#pragma unroll
            for (int nt = 0; nt < 4; ++nt) {
                short8 bfr = *(const short8*)(wt + (size_t)nt * 16 * CIN);
#pragma unroll
                for (int f = 0; f < 4; ++f)
                    acc[f][nt] = __builtin_amdgcn_mfma_f32_16x16x32_bf16(a[f], bfr, acc[f][nt], 0, 0, 0);
            }
        }
    }

    // Epilogue. C/D layout: col = lane&15 (=co offset), row = q*4 + reg (=pixel).
#pragma unroll
    for (int nt = 0; nt < 4; ++nt) {
        const int co = cog + nt * 16 + m;
        const float bb = bias[co];
#pragma unroll
        for (int f = 0; f < 4; ++f) {
#pragma unroll
            for (int r = 0; r < 4; ++r) {
                const int xp = x0 + f * 16 + q * 4 + r;
                const float v = fmaxf(acc[f][nt][r] + bb, 0.0f);
                out_i[((size_t)y * WW + xp) * COUT + co] = __float2bfloat16(v);
            }
        }
    }
}

// ---------------------------------------------------------------------------
// Head via MFMA: 3x3 conv (64 -> 16, co 11..15 zero) + per-pixel softmax over
// 11 channels, writing f32 planar [11][HW] per image. Same LDS staging; the
// pixel-major transpose for softmax goes through a padded-stride LDS buffer.
// ---------------------------------------------------------------------------
__global__ __launch_bounds__(256, 2) void head_mfma(const bf16* __restrict__ in,
                                                    const bf16* __restrict__ wrp, // [9][16][64]
                                                    const float* __restrict__ bias, // 11
                                                    float* __restrict__ outk_base,
                                                    int b0)
{
    __shared__ bf16  slab[6 * 66 * 32];    // 25344 B
    __shared__ float smx[4][64][17];       // 17408 B, stride 17 breaks conflicts

    const int tid  = threadIdx.x;
    const int lane = tid & 63;
    const int wv   = tid >> 6;
    const int m    = lane & 15;
    const int q    = lane >> 4;
    const int img  = blockIdx.y >> 6;
    const int x0   = blockIdx.x * 64;
    const int y0   = (blockIdx.y & 63) * 4;
    const int y    = y0 + wv;

    const bf16* in_i = in + (size_t)img * HW * 64;
    float* outk = outk_base + (size_t)(b0 + img) * 11 * HW;

    f32x4 acc[4];
#pragma unroll
    for (int f = 0; f < 4; ++f) acc[f] = (f32x4){0.f, 0.f, 0.f, 0.f};

    const short8 zero8 = {0, 0, 0, 0, 0, 0, 0, 0};

    for (int k0 = 0; k0 < 64; k0 += 32) {
        __syncthreads();
        for (int e = tid; e < 1584; e += 256) {
            const int row = e / 264;
            const int rem = e - row * 264;
            const int px  = rem >> 2;
            const int seg = rem & 3;
            const int yy  = y0 - 1 + row;
            const int xx  = x0 - 1 + px;
            short8 v = zero8;
            if (yy >= 0 && yy < HH && xx >= 0 && xx < WW)
                v = *(const short8*)(in_i + ((size_t)yy * WW + xx) * 64 + k0 + seg * 8);
            *(short8*)(&slab[(row * 66 + px) * 32 + seg * 8]) = v;
        }
        __syncthreads();

#pragma unroll
        for (int t = 0; t < 9; ++t) {
            const int dy = t / 3 - 1, dx = t % 3 - 1;
            const int row = wv + dy + 1;
            short8 bfr = *(const short8*)(wrp + (size_t)t * 16 * 64 + (size_t)m * 64 + k0 + q * 8);
#pragma unroll
            for (int f = 0; f < 4; ++f) {
                short8 a = *(const short8*)(&slab[(row * 66 + (f * 16 + m + dx + 1)) * 32 + q * 8]);
                acc[f] = __builtin_amdgcn_mfma_f32_16x16x32_bf16(a, bfr, acc[f], 0, 0, 0);
            }
        }
    }

    // scatter C (col=co=m, row=pixel=q*4+r) into per-wave pixel-major LDS
    const float bb = (m < 11) ? bias[m] : 0.0f;
#pragma unroll
    for (int f = 0; f < 4; ++f)
#pragma unroll
        for (int r = 0; r < 4; ++r)
            smx[wv][f * 16 + q * 4 + r][m] = acc[f][r] + bb;
    __syncthreads();   // cheap; guarantees LDS visibility before transpose read

    // lane = pixel within the wave's row; softmax over 11 channels
    float v[11];
#pragma unroll
    for (int j = 0; j < 11; ++j) v[j] = smx[wv][lane][j];
    float mx = v[0];
#pragma unroll
    for (int j = 1; j < 11; ++j) mx = fmaxf(mx, v[j]);
    float s = 0.0f;
#pragma unroll
    for (int j = 0; j < 11; ++j) { v[j] = expf(v[j] - mx); s += v[j]; }
    const float inv = 1.0f / s;

    float* op = outk + (size_t)y * WW + x0 + lane;
#pragma unroll
    for (int j = 0; j < 11; ++j)
        op[(size_t)j * HW] = v[j] * inv;
}

// ---------------------------------------------------------------------------
// Horizontal separable pass (full batch): h = sum_i kh_i * shift_x(rgb, i-5)
// ---------------------------------------------------------------------------
__global__ __launch_bounds__(256) void hpass(const float* __restrict__ rgb,
                                             const float* __restrict__ kh,
                                             float* __restrict__ h)
{
    int idx = blockIdx.x * 256 + threadIdx.x;     // b*HW + p, total 524288
    int b = idx >> 16;                            // HW = 2^16
    int p = idx & (HW - 1);
    int y = p >> 8;
    int x = p & 255;

    float kw[11];
#pragma unroll
    for (int i = 0; i < 11; ++i) kw[i] = kh[((size_t)(b * 11 + i)) * HW + p];

#pragma unroll
    for (int c = 0; c < 3; ++c) {
        const float* rp = rgb + ((size_t)(b * 3 + c)) * HW + (size_t)y * WW;
        float s = 0.0f;
#pragma unroll
        for (int i = 0; i < 11; ++i) {
            int xx = x + i - 5;
            if (xx >= 0 && xx < WW) s = fmaf(kw[i], rp[xx], s);
        }
        h[((size_t)(b * 3 + c)) * HW + p] = s;
    }
}

// ---------------------------------------------------------------------------
// Vertical pass + depth-mask composite. Writes final, blurred, mask.
// ---------------------------------------------------------------------------
__global__ __launch_bounds__(256) void vpass_compose(const float* __restrict__ h,
                                                     const float* __restrict__ kv,
                                                     const float* __restrict__ rgb,
                                                     const float* __restrict__ depth,
                                                     float* __restrict__ fin,
                                                     float* __restrict__ blur,
                                                     float* __restrict__ masko)
{
    int idx = blockIdx.x * 256 + threadIdx.x;
    int b = idx >> 16;                            // HW = 2^16
    int p = idx & (HW - 1);
    int y = p >> 8;
    int x = p & 255;

    float kw[11];
#pragma unroll
    for (int i = 0; i < 11; ++i) kw[i] = kv[((size_t)(b * 11 + i)) * HW + p];

    float d = depth[idx];
    float mk = (d > 0.2f) ? 1.0f : 0.0f;
    masko[idx] = mk;

#pragma unroll
    for (int c = 0; c < 3; ++c) {
        const float* hp = h + ((size_t)(b * 3 + c)) * HW + x;
        float s = 0.0f;
#pragma unroll
        for (int i = 0; i < 11; ++i) {
            int yy = y + i - 5;
            if (yy >= 0 && yy < HH) s = fmaf(kw[i], hp[(size_t)yy * WW], s);
        }
        size_t o = ((size_t)(b * 3 + c)) * HW + p;
        blur[o] = s;
        fin[o] = mk * rgb[o] + (1.0f - mk) * s;
    }
}

// ---------------------------------------------------------------------------
extern "C" void kernel_launch(void* const* d_in, const int* in_sizes, int n_in,
                              void* d_out, int out_size, void* d_ws, size_t ws_size,
                              hipStream_t stream)
{
    const float* rgb   = (const float*)d_in[0];
    const float* depth = (const float*)d_in[1];
    const float* w1 = (const float*)d_in[2];  const float* b1 = (const float*)d_in[3];
    const float* w2 = (const float*)d_in[4];  const float* b2 = (const float*)d_in[5];
    const float* w3 = (const float*)d_in[6];  const float* b3 = (const float*)d_in[7];
    const float* w4 = (const float*)d_in[8];  const float* b4 = (const float*)d_in[9];
    const float* w5 = (const float*)d_in[10]; const float* b5 = (const float*)d_in[11];
    const float* wh = (const float*)d_in[12]; const float* bh = (const float*)d_in[13];
    const float* wv = (const float*)d_in[14]; const float* bv = (const float*)d_in[15];

    float* out    = (float*)d_out;
    float* fin_o  = out;                    // [8,3,256,256]
    float* blur_o = out + 1572864;          // [8,3,256,256]
    float* kh_o   = out + 3145728;          // [8,11,256,256]
    float* kv_o   = out + 8912896;          // [8,11,256,256]
    float* mask_o = out + 14680064;         // [8,1,256,256]

    // --- Select batch group size G from ws_size (deterministic -> graph-safe).
    const size_t perG = (size_t)HW * 2 * (128 + 64 + 128);   // 41.9 MB per image
    const size_t wsz  = (size_t)1 * 1024 * 1024;
    int G = 1;
    if (ws_size >= 8 * perG + wsz) G = 8;
    else if (ws_size >= 4 * perG + wsz) G = 4;
    else if (ws_size >= 2 * perG + wsz) G = 2;

    char* ws = (char*)d_ws;
    const size_t szA = (size_t)G * HW * 128 * 2;
    const size_t szB = (size_t)G * HW * 64 * 2;
    const size_t szC = (size_t)G * HW * 128 * 2;
    bf16* bufA = (bf16*)ws;
    bf16* bufB = (bf16*)(ws + szA);
    bf16* bufC = (bf16*)(ws + szA + szB);
    float* hbuf = (float*)bufC;              // 6.3 MB <= szC

    bf16* w2r = (bf16*)(ws + szA + szB + szC);
    bf16* w3r = w2r + 9 * 64 * 64;
    bf16* w4r = w3r + 9 * 128 * 64;
    bf16* w5r = w4r + 9 * 128 * 128;
    bf16* whr = w5r + 9 * 64 * 128;
    bf16* wvr = whr + 9 * 16 * 64;

    dim3 blk(256);

    // one-time weight reorders (graph-safe: identical work every call)
    reorder_w<64, 64>  <<<dim3((9*64*64   + 255) / 256), blk, 0, stream>>>(w2, w2r);
    reorder_w<128, 64> <<<dim3((9*128*64  + 255) / 256), blk, 0, stream>>>(w3, w3r);
    reorder_w<128, 128><<<dim3((9*128*128 + 255) / 256), blk, 0, stream>>>(w4, w4r);
    reorder_w<64, 128> <<<dim3((9*64*128  + 255) / 256), blk, 0, stream>>>(w5, w5r);
    reorder_w_head     <<<dim3((9*16*64   + 255) / 256), blk, 0, stream>>>(wh, whr);
    reorder_w_head     <<<dim3((9*16*64   + 255) / 256), blk, 0, stream>>>(wv, wvr);

    const int GY = 64 * G;
    for (int b0 = 0; b0 < BB; b0 += G) {
        conv3x3_first<16>  <<<dim3(4, GY, 4), blk, 0, stream>>>(rgb, depth, w1, b1, bufA, b0);
        conv_mfma_lds<64>  <<<dim3(4, GY, 1), blk, 0, stream>>>(bufA, w2r, b2, bufB, 64);
        conv_mfma_lds<64>  <<<dim3(4, GY, 2), blk, 0, stream>>>(bufB, w3r, b3, bufC, 128);
        conv_mfma_lds<128> <<<dim3(4, GY, 2), blk, 0, stream>>>(bufC, w4r, b4, bufA, 128);
        conv_mfma_lds<128> <<<dim3(4, GY, 1), blk, 0, stream>>>(bufA, w5r, b5, bufB, 64);
        head_mfma          <<<dim3(4, GY, 1), blk, 0, stream>>>(bufB, whr, bh, kh_o, b0);
        head_mfma          <<<dim3(4, GY, 1), blk, 0, stream>>>(bufB, wvr, bv, kv_o, b0);
    }

    // separable blur + composite (full batch; bufC/f3 dead by now)
    hpass<<<dim3(2048), blk, 0, stream>>>(rgb, kh_o, hbuf);
    vpass_compose<<<dim3(2048), blk, 0, stream>>>(hbuf, kv_o, rgb, depth,
                                                  fin_o, blur_o, mask_o);
}

// Round 7
// 1151.645 us; speedup vs baseline: 10.9418x; 1.0642x over previous
//
#include <hip/hip_runtime.h>
#include <hip/hip_bf16.h>
#include <math.h>

// Problem constants (B=8, H=W=256, K=11 taps, thresh 0.2)
#define HH 256
#define WW 256
#define HW (HH*WW)
#define BB 8

typedef __hip_bfloat16 bf16;
typedef __attribute__((ext_vector_type(8))) short short8;   // 8 bf16 (4 VGPRs)
typedef __attribute__((ext_vector_type(4))) float f32x4;    // MFMA acc

// Padded px stride in the LDS slab: 40 elems = 80 B = 20 banks.
// gcd(20,32)=4 -> 64-lane b128 access touches each bank exactly 8x (minimum).
#define PXS 40

__device__ __forceinline__ float bflo(unsigned u) { return __uint_as_float(u << 16); }
__device__ __forceinline__ float bfhi(unsigned u) { return __uint_as_float(u & 0xffff0000u); }

// ---------------------------------------------------------------------------
// Weight reorder: OIHW f32 -> [t][co][ci] bf16 (t = ky*3+kx)
// ---------------------------------------------------------------------------
template<int CO, int CI>
__global__ __launch_bounds__(256) void reorder_w(const float* __restrict__ w,
                                                 bf16* __restrict__ wr)
{
    int idx = blockIdx.x * 256 + threadIdx.x;
    if (idx >= 9 * CO * CI) return;
    int ci = idx % CI;
    int co = (idx / CI) % CO;
    int t  = idx / (CI * CO);
    wr[idx] = __float2bfloat16(w[((size_t)co * CI + ci) * 9 + t]);
}

// Head weights: [11][64][3][3] f32 -> [t][16][64] bf16, co 11..15 zero-padded.
__global__ __launch_bounds__(256) void reorder_w_head(const float* __restrict__ w,
                                                      bf16* __restrict__ wr)
{
    int idx = blockIdx.x * 256 + threadIdx.x;
    if (idx >= 9 * 16 * 64) return;
    int ci = idx % 64;
    int co = (idx / 64) % 16;
    int t  = idx / (64 * 16);
    float v = (co < 11) ? w[((size_t)co * 64 + ci) * 9 + t] : 0.0f;
    wr[idx] = __float2bfloat16(v);
}

// ---------------------------------------------------------------------------
// conv1: 3x3 conv over concat(rgb,depth) [4ch f32 planar], ReLU,
// output NHWC bf16 [G][HW][64]. blockIdx.y = img*64 + ytile.
// ---------------------------------------------------------------------------
template<int COC>
__global__ __launch_bounds__(256) void conv3x3_first(const float* __restrict__ rgb,
                                                     const float* __restrict__ depth,
                                                     const float* __restrict__ w,
                                                     const float* __restrict__ bias,
                                                     bf16* __restrict__ out, int b0)
{
    const int tid = threadIdx.x;
    const int img = blockIdx.y >> 6;
    const int b   = b0 + img;
    const int x = blockIdx.x * 64 + (tid & 63);
    const int y = (blockIdx.y & 63) * 4 + (tid >> 6);
    const int cog = blockIdx.z * COC;

    const bool vy0 = (y > 0), vy2 = (y < HH - 1);
    const bool vx0 = (x > 0), vx2 = (x < WW - 1);
    bool val[9];
    int  off[9];
    {
        int t = 0;
        for (int dy = -1; dy <= 1; ++dy)
            for (int dx = -1; dx <= 1; ++dx) {
                val[t] = (dy < 0 ? vy0 : (dy > 0 ? vy2 : true)) &&
                         (dx < 0 ? vx0 : (dx > 0 ? vx2 : true));
                off[t] = dy * WW + dx;
                ++t;
            }
    }

    float acc[COC];
#pragma unroll
    for (int j = 0; j < COC; ++j) acc[j] = bias[cog + j];

    const int p0 = y * WW + x;
#pragma unroll
    for (int ci = 0; ci < 4; ++ci) {
        const float* p = (ci < 3) ? (rgb + ((size_t)(b * 3 + ci)) * HW + p0)
                                  : (depth + (size_t)b * HW + p0);
        float v[9];
#pragma unroll
        for (int t = 0; t < 9; ++t)
            v[t] = val[t] ? p[off[t]] : 0.0f;

        const float* wp = w + ((size_t)cog * 4 + ci) * 9;
#pragma unroll
        for (int j = 0; j < COC; ++j) {
            const float* wj = wp + (size_t)j * 4 * 9;
#pragma unroll
            for (int t = 0; t < 9; ++t)
                acc[j] = fmaf(wj[t], v[t], acc[j]);
        }
    }

    bf16* op = out + (size_t)img * HW * 64 + (size_t)p0 * 64 + cog;
#pragma unroll
    for (int j = 0; j < COC; ++j)
        op[j] = __float2bfloat16(fmaxf(acc[j], 0.0f));
}

// ---------------------------------------------------------------------------
// LDS-staged MFMA implicit-GEMM 3x3 conv, batched over G images.
// in : NHWC bf16 [G][HW][CIN]   wr : bf16 [9][COUT][CIN]   out : [G][HW][COUT]
// Block = 4 waves = 64px x 4rows; each wave computes NT*16 couts for its row.
// Slab layout padded to PXS=40 elems/px -> bank-conflict-free b128 access.
// NT=8 (128 co) halves LDS reads per MFMA vs NT=4.
// ---------------------------------------------------------------------------
template<int CIN, int COUT, int NT, int WPB>
__global__ __launch_bounds__(256, WPB) void conv_mfma_lds(const bf16* __restrict__ in,
                                                          const bf16* __restrict__ wr,
                                                          const float* __restrict__ bias,
                                                          bf16* __restrict__ out)
{
    __shared__ bf16 slab[6 * 66 * PXS];    // 31,680 B

    const int tid  = threadIdx.x;
    const int lane = tid & 63;
    const int wv   = tid >> 6;
    const int m    = lane & 15;
    const int q    = lane >> 4;
    const int img  = blockIdx.y >> 6;
    const int x0   = blockIdx.x * 64;
    const int y0   = (blockIdx.y & 63) * 4;
    const int y    = y0 + wv;

    const bf16* in_i  = in  + (size_t)img * HW * CIN;
    bf16*       out_i = out + (size_t)img * HW * COUT;

    f32x4 acc[4][NT];
#pragma unroll
    for (int f = 0; f < 4; ++f)
#pragma unroll
        for (int nt = 0; nt < NT; ++nt)
            acc[f][nt] = (f32x4){0.f, 0.f, 0.f, 0.f};

    const short8 zero8 = {0, 0, 0, 0, 0, 0, 0, 0};

    for (int k0 = 0; k0 < CIN; k0 += 32) {
        __syncthreads();                   // previous chunk's readers done
        // stage [6 rows][66 px][32 ch] (pad elems 32..39 untouched)
        for (int e = tid; e < 1584; e += 256) {
            const int row = e / 264;       // 264 = 66*4
            const int rem = e - row * 264;
            const int px  = rem >> 2;
            const int seg = rem & 3;
            const int yy  = y0 - 1 + row;
            const int xx  = x0 - 1 + px;
            short8 v = zero8;
            if (yy >= 0 && yy < HH && xx >= 0 && xx < WW)
                v = *(const short8*)(in_i + ((size_t)yy * WW + xx) * CIN + k0 + seg * 8);
            *(short8*)(&slab[(row * 66 + px) * PXS + seg * 8]) = v;
        }
        __syncthreads();

#pragma unroll
        for (int t = 0; t < 9; ++t) {
            const int dy = t / 3 - 1, dx = t % 3 - 1;
            const int row = wv + dy + 1;   // 0..5
            short8 a[4];
#pragma unroll
            for (int f = 0; f < 4; ++f)
                a[f] = *(const short8*)(&slab[(row * 66 + (f * 16 + m + dx + 1)) * PXS + q * 8]);
            const bf16* wt = wr + (size_t)t * COUT * CIN + (size_t)m * CIN + k0 + q * 8;
#pragma unroll
            for (int nt = 0; nt < NT; ++nt) {
                short8 bfr = *(const short8*)(wt + (size_t)nt * 16 * CIN);
#pragma unroll
                for (int f = 0; f < 4; ++f)
                    acc[f][nt] = __builtin_amdgcn_mfma_f32_16x16x32_bf16(a[f], bfr, acc[f][nt], 0, 0, 0);
            }
        }
    }

    // Epilogue. C/D layout: col = lane&15 (=co offset), row = q*4 + reg (=pixel).
#pragma unroll
    for (int nt = 0; nt < NT; ++nt) {
        const int co = nt * 16 + m;
        const float bb = bias[co];
#pragma unroll
        for (int f = 0; f < 4; ++f) {
#pragma unroll
            for (int r = 0; r < 4; ++r) {
                const int xp = x0 + f * 16 + q * 4 + r;
                const float v = fmaxf(acc[f][nt][r] + bb, 0.0f);
                out_i[((size_t)y * WW + xp) * COUT + co] = __float2bfloat16(v);
            }
        }
    }
}

// ---------------------------------------------------------------------------
// Head via MFMA: 3x3 conv (64 -> 16, co 11..15 zero) + per-pixel softmax over
// 11 channels, writing f32 planar [11][HW] per image.
// ---------------------------------------------------------------------------
__global__ __launch_bounds__(256, 2) void head_mfma(const bf16* __restrict__ in,
                                                    const bf16* __restrict__ wrp, // [9][16][64]
                                                    const float* __restrict__ bias, // 11
                                                    float* __restrict__ outk_base,
                                                    int b0)
{
    __shared__ bf16  slab[6 * 66 * PXS];   // 31,680 B
    __shared__ float smx[4][64][17];       // 17,408 B

    const int tid  = threadIdx.x;
    const int lane = tid & 63;
    const int wv   = tid >> 6;
    const int m    = lane & 15;
    const int q    = lane >> 4;
    const int img  = blockIdx.y >> 6;
    const int x0   = blockIdx.x * 64;
    const int y0   = (blockIdx.y & 63) * 4;
    const int y    = y0 + wv;

    const bf16* in_i = in + (size_t)img * HW * 64;
    float* outk = outk_base + (size_t)(b0 + img) * 11 * HW;

    f32x4 acc[4];
#pragma unroll
    for (int f = 0; f < 4; ++f) acc[f] = (f32x4){0.f, 0.f, 0.f, 0.f};

    const short8 zero8 = {0, 0, 0, 0, 0, 0, 0, 0};

    for (int k0 = 0; k0 < 64; k0 += 32) {
        __syncthreads();
        for (int e = tid; e < 1584; e += 256) {
            const int row = e / 264;
            const int rem = e - row * 264;
            const int px  = rem >> 2;
            const int seg = rem & 3;
            const int yy  = y0 - 1 + row;
            const int xx  = x0 - 1 + px;
            short8 v = zero8;
            if (yy >= 0 && yy < HH && xx >= 0 && xx < WW)
                v = *(const short8*)(in_i + ((size_t)yy * WW + xx) * 64 + k0 + seg * 8);
            *(short8*)(&slab[(row * 66 + px) * PXS + seg * 8]) = v;
        }
        __syncthreads();

#pragma unroll
        for (int t = 0; t < 9; ++t) {
            const int dy = t / 3 - 1, dx = t % 3 - 1;
            const int row = wv + dy + 1;
            short8 bfr = *(const short8*)(wrp + (size_t)t * 16 * 64 + (size_t)m * 64 + k0 + q * 8);
#pragma unroll
            for (int f = 0; f < 4; ++f) {
                short8 a = *(const short8*)(&slab[(row * 66 + (f * 16 + m + dx + 1)) * PXS + q * 8]);
                acc[f] = __builtin_amdgcn_mfma_f32_16x16x32_bf16(a, bfr, acc[f], 0, 0, 0);
            }
        }
    }

    // scatter C (col=co=m, row=pixel=q*4+r) into per-wave pixel-major LDS
    const float bb = (m < 11) ? bias[m] : 0.0f;
#pragma unroll
    for (int f = 0; f < 4; ++f)
#pragma unroll
        for (int r = 0; r < 4; ++r)
            smx[wv][f * 16 + q * 4 + r][m] = acc[f][r] + bb;
    __syncthreads();

    // lane = pixel within the wave's row; softmax over 11 channels
    float v[11];
#pragma unroll
    for (int j = 0; j < 11; ++j) v[j] = smx[wv][lane][j];
    float mx = v[0];
#pragma unroll
    for (int j = 1; j < 11; ++j) mx = fmaxf(mx, v[j]);
    float s = 0.0f;
#pragma unroll
    for (int j = 0; j < 11; ++j) { v[j] = expf(v[j] - mx); s += v[j]; }
    const float inv = 1.0f / s;

    float* op = outk + (size_t)y * WW + x0 + lane;
#pragma unroll
    for (int j = 0; j < 11; ++j)
        op[(size_t)j * HW] = v[j] * inv;
}

// ---------------------------------------------------------------------------
// Horizontal separable pass (full batch): h = sum_i kh_i * shift_x(rgb, i-5)
// ---------------------------------------------------------------------------
__global__ __launch_bounds__(256) void hpass(const float* __restrict__ rgb,
                                             const float* __restrict__ kh,
                                             float* __restrict__ h)
{
    int idx = blockIdx.x * 256 + threadIdx.x;     // b*HW + p, total 524288
    int b = idx >> 16;                            // HW = 2^16
    int p = idx & (HW - 1);
    int y = p >> 8;
    int x = p & 255;

    float kw[11];
#pragma unroll
    for (int i = 0; i < 11; ++i) kw[i] = kh[((size_t)(b * 11 + i)) * HW + p];

#pragma unroll
    for (int c = 0; c < 3; ++c) {
        const float* rp = rgb + ((size_t)(b * 3 + c)) * HW + (size_t)y * WW;
        float s = 0.0f;
#pragma unroll
        for (int i = 0; i < 11; ++i) {
            int xx = x + i - 5;
            if (xx >= 0 && xx < WW) s = fmaf(kw[i], rp[xx], s);
        }
        h[((size_t)(b * 3 + c)) * HW + p] = s;
    }
}

// ---------------------------------------------------------------------------
// Vertical pass + depth-mask composite. Writes final, blurred, mask.
// ---------------------------------------------------------------------------
__global__ __launch_bounds__(256) void vpass_compose(const float* __restrict__ h,
                                                     const float* __restrict__ kv,
                                                     const float* __restrict__ rgb,
                                                     const float* __restrict__ depth,
                                                     float* __restrict__ fin,
                                                     float* __restrict__ blur,
                                                     float* __restrict__ masko)
{
    int idx = blockIdx.x * 256 + threadIdx.x;
    int b = idx >> 16;                            // HW = 2^16
    int p = idx & (HW - 1);
    int y = p >> 8;
    int x = p & 255;

    float kw[11];
#pragma unroll
    for (int i = 0; i < 11; ++i) kw[i] = kv[((size_t)(b * 11 + i)) * HW + p];

    float d = depth[idx];
    float mk = (d > 0.2f) ? 1.0f : 0.0f;
    masko[idx] = mk;

#pragma unroll
    for (int c = 0; c < 3; ++c) {
        const float* hp = h + ((size_t)(b * 3 + c)) * HW + x;
        float s = 0.0f;
#pragma unroll
        for (int i = 0; i < 11; ++i) {
            int yy = y + i - 5;
            if (yy >= 0 && yy < HH) s = fmaf(kw[i], hp[(size_t)yy * WW], s);
        }
        size_t o = ((size_t)(b * 3 + c)) * HW + p;
        blur[o] = s;
        fin[o] = mk * rgb[o] + (1.0f - mk) * s;
    }
}

// ---------------------------------------------------------------------------
extern "C" void kernel_launch(void* const* d_in, const int* in_sizes, int n_in,
                              void* d_out, int out_size, void* d_ws, size_t ws_size,
                              hipStream_t stream)
{
    const float* rgb   = (const float*)d_in[0];
    const float* depth = (const float*)d_in[1];
    const float* w1 = (const float*)d_in[2];  const float* b1 = (const float*)d_in[3];
    const float* w2 = (const float*)d_in[4];  const float* b2 = (const float*)d_in[5];
    const float* w3 = (const float*)d_in[6];  const float* b3 = (const float*)d_in[7];
    const float* w4 = (const float*)d_in[8];  const float* b4 = (const float*)d_in[9];
    const float* w5 = (const float*)d_in[10]; const float* b5 = (const float*)d_in[11];
    const float* wh = (const float*)d_in[12]; const float* bh = (const float*)d_in[13];
    const float* wv = (const float*)d_in[14]; const float* bv = (const float*)d_in[15];

    float* out    = (float*)d_out;
    float* fin_o  = out;                    // [8,3,256,256]
    float* blur_o = out + 1572864;          // [8,3,256,256]
    float* kh_o   = out + 3145728;          // [8,11,256,256]
    float* kv_o   = out + 8912896;          // [8,11,256,256]
    float* mask_o = out + 14680064;         // [8,1,256,256]

    // --- Select batch group size G from ws_size (deterministic -> graph-safe).
    const size_t perG = (size_t)HW * 2 * (128 + 64 + 128);   // 41.9 MB per image
    const size_t wsz  = (size_t)1 * 1024 * 1024;
    int G = 1;
    if (ws_size >= 8 * perG + wsz) G = 8;
    else if (ws_size >= 4 * perG + wsz) G = 4;
    else if (ws_size >= 2 * perG + wsz) G = 2;

    char* ws = (char*)d_ws;
    const size_t szA = (size_t)G * HW * 128 * 2;
    const size_t szB = (size_t)G * HW * 64 * 2;
    const size_t szC = (size_t)G * HW * 128 * 2;
    bf16* bufA = (bf16*)ws;
    bf16* bufB = (bf16*)(ws + szA);
    bf16* bufC = (bf16*)(ws + szA + szB);
    float* hbuf = (float*)bufC;              // 6.3 MB <= szC

    bf16* w2r = (bf16*)(ws + szA + szB + szC);
    bf16* w3r = w2r + 9 * 64 * 64;
    bf16* w4r = w3r + 9 * 128 * 64;
    bf16* w5r = w4r + 9 * 128 * 128;
    bf16* whr = w5r + 9 * 64 * 128;
    bf16* wvr = whr + 9 * 16 * 64;

    dim3 blk(256);

    // one-time weight reorders (graph-safe: identical work every call)
    reorder_w<64, 64>  <<<dim3((9*64*64   + 255) / 256), blk, 0, stream>>>(w2, w2r);
    reorder_w<128, 64> <<<dim3((9*128*64  + 255) / 256), blk, 0, stream>>>(w3, w3r);
    reorder_w<128, 128><<<dim3((9*128*128 + 255) / 256), blk, 0, stream>>>(w4, w4r);
    reorder_w<64, 128> <<<dim3((9*64*128  + 255) / 256), blk, 0, stream>>>(w5, w5r);
    reorder_w_head     <<<dim3((9*16*64   + 255) / 256), blk, 0, stream>>>(wh, whr);
    reorder_w_head     <<<dim3((9*16*64   + 255) / 256), blk, 0, stream>>>(wv, wvr);

    const int GY = 64 * G;
    for (int b0 = 0; b0 < BB; b0 += G) {
        conv3x3_first<16>           <<<dim3(4, GY, 4), blk, 0, stream>>>(rgb, depth, w1, b1, bufA, b0);
        conv_mfma_lds<64, 64, 4, 4> <<<dim3(4, GY), blk, 0, stream>>>(bufA, w2r, b2, bufB);
        conv_mfma_lds<64, 128, 8, 2><<<dim3(4, GY), blk, 0, stream>>>(bufB, w3r, b3, bufC);
        conv_mfma_lds<128,128, 8, 2><<<dim3(4, GY), blk, 0, stream>>>(bufC, w4r, b4, bufA);
        conv_mfma_lds<128, 64, 4, 4><<<dim3(4, GY), blk, 0, stream>>>(bufA, w5r, b5, bufB);
        head_mfma                   <<<dim3(4, GY), blk, 0, stream>>>(bufB, whr, bh, kh_o, b0);
        head_mfma                   <<<dim3(4, GY), blk, 0, stream>>>(bufB, wvr, bv, kv_o, b0);
    }

    // separable blur + composite (full batch; bufC/f3 dead by now)
    hpass<<<dim3(2048), blk, 0, stream>>>(rgb, kh_o, hbuf);
    vpass_compose<<<dim3(2048), blk, 0, stream>>>(hbuf, kv_o, rgb, depth,
                                                  fin_o, blur_o, mask_o);
}

// Round 8
// 1148.825 us; speedup vs baseline: 10.9687x; 1.0025x over previous
//
#include <hip/hip_runtime.h>
#include <hip/hip_bf16.h>
#include <math.h>

// Problem constants (B=8, H=W=256, K=11 taps, thresh 0.2)
#define HH 256
#define WW 256
#define HW (HH*WW)
#define BB 8

typedef __hip_bfloat16 bf16;
typedef __attribute__((ext_vector_type(8))) short short8;   // 8 bf16 (4 VGPRs)
typedef __attribute__((ext_vector_type(4))) float f32x4;    // MFMA acc

// async global->LDS, 16B per lane; LDS dest = wave-uniform base + lane*16
typedef __attribute__((address_space(3))) unsigned int lds_uint;
typedef const __attribute__((address_space(1))) unsigned int glob_uint;
__device__ __forceinline__ void dma16(const void* g, void* l) {
    __builtin_amdgcn_global_load_lds((glob_uint*)g, (lds_uint*)l, 16, 0, 0);
}

// Slab: [6 rows][66 px][32 ch] bf16, 64 B per px. Linear unit u (16 B) =
// (row*66+px)*4 + slot. XOR swizzle: LDS slot s of pixel px holds global
// channel-octet seg = s ^ (px&3)  -> wave64 b128 reads hit every bank
// exactly 8x (conflict-free minimum).
#define SLAB_ELEMS (6 * 66 * 32)
#define SLAB_UNITS 1584

// ---------------------------------------------------------------------------
// Weight reorder: OIHW f32 -> [t][co][ci] bf16 (t = ky*3+kx)
// ---------------------------------------------------------------------------
template<int CO, int CI>
__global__ __launch_bounds__(256) void reorder_w(const float* __restrict__ w,
                                                 bf16* __restrict__ wr)
{
    int idx = blockIdx.x * 256 + threadIdx.x;
    if (idx >= 9 * CO * CI) return;
    int ci = idx % CI;
    int co = (idx / CI) % CO;
    int t  = idx / (CI * CO);
    wr[idx] = __float2bfloat16(w[((size_t)co * CI + ci) * 9 + t]);
}

// Both head weights -> one [9][32][64] bf16 buffer: co 0..10 = wh, 16..26 = wv,
// rest zero-padded.
__global__ __launch_bounds__(256) void reorder_w_head2(const float* __restrict__ wh,
                                                       const float* __restrict__ wv,
                                                       bf16* __restrict__ wr)
{
    int idx = blockIdx.x * 256 + threadIdx.x;
    if (idx >= 9 * 32 * 64) return;
    int ci = idx % 64;
    int co = (idx / 64) % 32;
    int t  = idx / (64 * 32);
    const float* src = (co < 16) ? wh : wv;
    int c = co & 15;
    float v = (c < 11) ? src[((size_t)c * 64 + ci) * 9 + t] : 0.0f;
    wr[idx] = __float2bfloat16(v);
}

// ---------------------------------------------------------------------------
// Pre-zero the OOB halo slots of both slab buffers (those units are never
// written by the DMA -> stay zero for every K-chunk).
// ---------------------------------------------------------------------------
__device__ __forceinline__ void zero_halo(bf16* slab0, bf16* slab1,
                                          int tid, int x0, int y0)
{
    const short8 z8 = {0,0,0,0,0,0,0,0};
    for (int e = tid; e < SLAB_UNITS; e += 256) {
        int row = e / 264, rem = e - row * 264;
        int px = rem >> 2;
        int yy = y0 - 1 + row, xx = x0 - 1 + px;
        if (yy < 0 || yy >= HH || xx < 0 || xx >= WW) {
            *(short8*)(slab0 + e * 8) = z8;
            *(short8*)(slab1 + e * 8) = z8;
        }
    }
}

// Issue the DMA for one 32-ch chunk into one slab buffer. Called by ONE wave.
template<int CIN>
__device__ __forceinline__ void issue_dma(const bf16* in_i, bf16* slab,
                                          int lane, int x0, int y0, int k0)
{
    for (int it = 0; it < 25; ++it) {
        int u = it * 64 + lane;
        int row = u / 264, rem = u - row * 264;
        int px = rem >> 2, slot = rem & 3;
        int seg = slot ^ (px & 3);
        int yy = y0 - 1 + row, xx = x0 - 1 + px;
        bool val = (u < SLAB_UNITS) && (yy >= 0) && (yy < HH) && (xx >= 0) && (xx < WW);
        const bf16* g = in_i + ((size_t)(yy * WW + xx)) * CIN + k0 + seg * 8;
        bf16* l = slab + (size_t)it * 512;        // it*64 lanes * 8 elems
        if (val) dma16(g, l);
    }
}

// ---------------------------------------------------------------------------
// conv1: 3x3 conv over concat(rgb,depth) [4ch f32 planar], ReLU,
// output NHWC bf16 [G][HW][64]. blockIdx.y = img*64 + ytile.
// ---------------------------------------------------------------------------
template<int COC>
__global__ __launch_bounds__(256) void conv3x3_first(const float* __restrict__ rgb,
                                                     const float* __restrict__ depth,
                                                     const float* __restrict__ w,
                                                     const float* __restrict__ bias,
                                                     bf16* __restrict__ out, int b0)
{
    const int tid = threadIdx.x;
    const int img = blockIdx.y >> 6;
    const int b   = b0 + img;
    const int x = blockIdx.x * 64 + (tid & 63);
    const int y = (blockIdx.y & 63) * 4 + (tid >> 6);
    const int cog = blockIdx.z * COC;

    const bool vy0 = (y > 0), vy2 = (y < HH - 1);
    const bool vx0 = (x > 0), vx2 = (x < WW - 1);
    bool val[9];
    int  off[9];
    {
        int t = 0;
        for (int dy = -1; dy <= 1; ++dy)
            for (int dx = -1; dx <= 1; ++dx) {
                val[t] = (dy < 0 ? vy0 : (dy > 0 ? vy2 : true)) &&
                         (dx < 0 ? vx0 : (dx > 0 ? vx2 : true));
                off[t] = dy * WW + dx;
                ++t;
            }
    }

    float acc[COC];
#pragma unroll
    for (int j = 0; j < COC; ++j) acc[j] = bias[cog + j];

    const int p0 = y * WW + x;
#pragma unroll
    for (int ci = 0; ci < 4; ++ci) {
        const float* p = (ci < 3) ? (rgb + ((size_t)(b * 3 + ci)) * HW + p0)
                                  : (depth + (size_t)b * HW + p0);
        float v[9];
#pragma unroll
        for (int t = 0; t < 9; ++t)
            v[t] = val[t] ? p[off[t]] : 0.0f;

        const float* wp = w + ((size_t)cog * 4 + ci) * 9;
#pragma unroll
        for (int j = 0; j < COC; ++j) {
            const float* wj = wp + (size_t)j * 4 * 9;
#pragma unroll
            for (int t = 0; t < 9; ++t)
                acc[j] = fmaf(wj[t], v[t], acc[j]);
        }
    }

    bf16* op = out + (size_t)img * HW * 64 + (size_t)p0 * 64 + cog;
#pragma unroll
    for (int j = 0; j < COC; ++j)
        op[j] = __float2bfloat16(fmaxf(acc[j], 0.0f));
}

// ---------------------------------------------------------------------------
// Pipelined MFMA implicit-GEMM 3x3 conv: double-buffered DMA-staged slab,
// ONE barrier per K-chunk, rotating designated DMA wave.
// in : NHWC bf16 [G][HW][CIN]   wr : bf16 [9][COUT][CIN]   out : [G][HW][COUT]
// ---------------------------------------------------------------------------
template<int CIN, int COUT, int NT, int WPB>
__global__ __launch_bounds__(256, WPB) void conv_mfma_pipe(const bf16* __restrict__ in,
                                                           const bf16* __restrict__ wr,
                                                           const float* __restrict__ bias,
                                                           bf16* __restrict__ out)
{
    constexpr int NCH = CIN / 32;
    __shared__ bf16 slab[2][SLAB_ELEMS];     // 2 x 25,344 B

    const int tid  = threadIdx.x;
    const int lane = tid & 63;
    const int wv   = tid >> 6;
    const int m    = lane & 15;
    const int q    = lane >> 4;
    const int img  = blockIdx.y >> 6;
    const int x0   = blockIdx.x * 64;
    const int y0   = (blockIdx.y & 63) * 4;
    const int y    = y0 + wv;

    const bf16* in_i  = in  + (size_t)img * HW * CIN;
    bf16*       out_i = out + (size_t)img * HW * COUT;

    zero_halo(slab[0], slab[1], tid, x0, y0);

    f32x4 acc[4][NT];
#pragma unroll
    for (int f = 0; f < 4; ++f)
#pragma unroll
        for (int nt = 0; nt < NT; ++nt)
            acc[f][nt] = (f32x4){0.f, 0.f, 0.f, 0.f};

    // prime chunk 0
    if (wv == 0) issue_dma<CIN>(in_i, slab[0], lane, x0, y0, 0);

    for (int kc = 0; kc < NCH; ++kc) {
        __syncthreads();   // compiler drains vmcnt -> chunk kc resident in LDS
        if (kc + 1 < NCH && wv == ((kc + 1) & 3))
            issue_dma<CIN>(in_i, slab[(kc + 1) & 1], lane, x0, y0, (kc + 1) * 32);

        const bf16* sl = slab[kc & 1];
        const int k0 = kc * 32;
#pragma unroll
        for (int t = 0; t < 9; ++t) {
            const int dy = t / 3 - 1, dx = t % 3 - 1;
            const int row = wv + dy + 1;   // 0..5
            short8 a[4];
#pragma unroll
            for (int f = 0; f < 4; ++f) {
                const int px = f * 16 + m + dx + 1;
                const int slot = q ^ (px & 3);
                a[f] = *(const short8*)(sl + (row * 66 + px) * 32 + slot * 8);
            }
            const bf16* wt = wr + (size_t)t * COUT * CIN + (size_t)m * CIN + k0 + q * 8;
#pragma unroll
            for (int nt = 0; nt < NT; ++nt) {
                short8 bfr = *(const short8*)(wt + (size_t)nt * 16 * CIN);
#pragma unroll
                for (int f = 0; f < 4; ++f)
                    acc[f][nt] = __builtin_amdgcn_mfma_f32_16x16x32_bf16(a[f], bfr, acc[f][nt], 0, 0, 0);
            }
        }
    }

    // Epilogue. C/D layout: col = lane&15 (=co offset), row = q*4 + reg (=pixel).
#pragma unroll
    for (int nt = 0; nt < NT; ++nt) {
        const int co = nt * 16 + m;
        const float bb = bias[co];
#pragma unroll
        for (int f = 0; f < 4; ++f) {
#pragma unroll
            for (int r = 0; r < 4; ++r) {
                const int xp = x0 + f * 16 + q * 4 + r;
                const float v = fmaxf(acc[f][nt][r] + bb, 0.0f);
                out_i[((size_t)y * WW + xp) * COUT + co] = __float2bfloat16(v);
            }
        }
    }
}

// ---------------------------------------------------------------------------
// Merged heads: one pipelined kernel computes BOTH kh and kv (shared staging).
// weights [9][32][64] (co 0..15 = wh-padded, 16..31 = wv-padded); per-pixel
// softmax over 11 channels via wave-private padded LDS transpose.
// ---------------------------------------------------------------------------
__global__ __launch_bounds__(256, 2) void head_mfma2(const bf16* __restrict__ in,
                                                     const bf16* __restrict__ wrp,
                                                     const float* __restrict__ bh,
                                                     const float* __restrict__ bv,
                                                     float* __restrict__ kh_base,
                                                     float* __restrict__ kv_base,
                                                     int b0)
{
    __shared__ bf16  slab[2][SLAB_ELEMS];   // 2 x 25,344 B
    __shared__ float smx[4][64][17];        // 17,408 B (wave-private slices)

    const int tid  = threadIdx.x;
    const int lane = tid & 63;
    const int wv   = tid >> 6;
    const int m    = lane & 15;
    const int q    = lane >> 4;
    const int img  = blockIdx.y >> 6;
    const int x0   = blockIdx.x * 64;
    const int y0   = (blockIdx.y & 63) * 4;
    const int y    = y0 + wv;

    const bf16* in_i = in + (size_t)img * HW * 64;

    zero_halo(slab[0], slab[1], tid, x0, y0);

    f32x4 acc[4][2];
#pragma unroll
    for (int f = 0; f < 4; ++f) { acc[f][0] = (f32x4){0.f,0.f,0.f,0.f}; acc[f][1] = (f32x4){0.f,0.f,0.f,0.f}; }

    if (wv == 0) issue_dma<64>(in_i, slab[0], lane, x0, y0, 0);

    for (int kc = 0; kc < 2; ++kc) {
        __syncthreads();
        if (kc == 0 && wv == 1)
            issue_dma<64>(in_i, slab[1], lane, x0, y0, 32);

        const bf16* sl = slab[kc & 1];
        const int k0 = kc * 32;
#pragma unroll
        for (int t = 0; t < 9; ++t) {
            const int dy = t / 3 - 1, dx = t % 3 - 1;
            const int row = wv + dy + 1;
            short8 a[4];
#pragma unroll
            for (int f = 0; f < 4; ++f) {
                const int px = f * 16 + m + dx + 1;
                const int slot = q ^ (px & 3);
                a[f] = *(const short8*)(sl + (row * 66 + px) * 32 + slot * 8);
            }
            const bf16* wt = wrp + (size_t)t * 32 * 64 + (size_t)m * 64 + k0 + q * 8;
#pragma unroll
            for (int nt = 0; nt < 2; ++nt) {
                short8 bfr = *(const short8*)(wt + (size_t)nt * 16 * 64);
#pragma unroll
                for (int f = 0; f < 4; ++f)
                    acc[f][nt] = __builtin_amdgcn_mfma_f32_16x16x32_bf16(a[f], bfr, acc[f][nt], 0, 0, 0);
            }
        }
    }

    // two heads sequentially; smx slice is wave-private (no barrier needed)
#pragma unroll
    for (int head = 0; head < 2; ++head) {
        const float* bias = head ? bv : bh;
        const float bb = (m < 11) ? bias[m] : 0.0f;
#pragma unroll
        for (int f = 0; f < 4; ++f)
#pragma unroll
            for (int r = 0; r < 4; ++r)
                smx[wv][f * 16 + q * 4 + r][m] = acc[f][head][r] + bb;

        float v[11];
#pragma unroll
        for (int j = 0; j < 11; ++j) v[j] = smx[wv][lane][j];
        float mx = v[0];
#pragma unroll
        for (int j = 1; j < 11; ++j) mx = fmaxf(mx, v[j]);
        float s = 0.0f;
#pragma unroll
        for (int j = 0; j < 11; ++j) { v[j] = expf(v[j] - mx); s += v[j]; }
        const float inv = 1.0f / s;

        float* op = (head ? kv_base : kh_base) + (size_t)(b0 + img) * 11 * HW
                    + (size_t)y * WW + x0 + lane;
#pragma unroll
        for (int j = 0; j < 11; ++j)
            op[(size_t)j * HW] = v[j] * inv;
    }
}

// ---------------------------------------------------------------------------
// Horizontal separable pass (full batch): h = sum_i kh_i * shift_x(rgb, i-5)
// ---------------------------------------------------------------------------
__global__ __launch_bounds__(256) void hpass(const float* __restrict__ rgb,
                                             const float* __restrict__ kh,
                                             float* __restrict__ h)
{
    int idx = blockIdx.x * 256 + threadIdx.x;     // b*HW + p, total 524288
    int b = idx >> 16;                            // HW = 2^16
    int p = idx & (HW - 1);
    int y = p >> 8;
    int x = p & 255;

    float kw[11];
#pragma unroll
    for (int i = 0; i < 11; ++i) kw[i] = kh[((size_t)(b * 11 + i)) * HW + p];

#pragma unroll
    for (int c = 0; c < 3; ++c) {
        const float* rp = rgb + ((size_t)(b * 3 + c)) * HW + (size_t)y * WW;
        float s = 0.0f;
#pragma unroll
        for (int i = 0; i < 11; ++i) {
            int xx = x + i - 5;
            if (xx >= 0 && xx < WW) s = fmaf(kw[i], rp[xx], s);
        }
        h[((size_t)(b * 3 + c)) * HW + p] = s;
    }
}

// ---------------------------------------------------------------------------
// Vertical pass + depth-mask composite. Writes final, blurred, mask.
// ---------------------------------------------------------------------------
__global__ __launch_bounds__(256) void vpass_compose(const float* __restrict__ h,
                                                     const float* __restrict__ kv,
                                                     const float* __restrict__ rgb,
                                                     const float* __restrict__ depth,
                                                     float* __restrict__ fin,
                                                     float* __restrict__ blur,
                                                     float* __restrict__ masko)
{
    int idx = blockIdx.x * 256 + threadIdx.x;
    int b = idx >> 16;                            // HW = 2^16
    int p = idx & (HW - 1);
    int y = p >> 8;
    int x = p & 255;

    float kw[11];
#pragma unroll
    for (int i = 0; i < 11; ++i) kw[i] = kv[((size_t)(b * 11 + i)) * HW + p];

    float d = depth[idx];
    float mk = (d > 0.2f) ? 1.0f : 0.0f;
    masko[idx] = mk;

#pragma unroll
    for (int c = 0; c < 3; ++c) {
        const float* hp = h + ((size_t)(b * 3 + c)) * HW + x;
        float s = 0.0f;
#pragma unroll
        for (int i = 0; i < 11; ++i) {
            int yy = y + i - 5;
            if (yy >= 0 && yy < HH) s = fmaf(kw[i], hp[(size_t)yy * WW], s);
        }
        size_t o = ((size_t)(b * 3 + c)) * HW + p;
        blur[o] = s;
        fin[o] = mk * rgb[o] + (1.0f - mk) * s;
    }
}

// ---------------------------------------------------------------------------
extern "C" void kernel_launch(void* const* d_in, const int* in_sizes, int n_in,
                              void* d_out, int out_size, void* d_ws, size_t ws_size,
                              hipStream_t stream)
{
    const float* rgb   = (const float*)d_in[0];
    const float* depth = (const float*)d_in[1];
    const float* w1 = (const float*)d_in[2];  const float* b1 = (const float*)d_in[3];
    const float* w2 = (const float*)d_in[4];  const float* b2 = (const float*)d_in[5];
    const float* w3 = (const float*)d_in[6];  const float* b3 = (const float*)d_in[7];
    const float* w4 = (const float*)d_in[8];  const float* b4 = (const float*)d_in[9];
    const float* w5 = (const float*)d_in[10]; const float* b5 = (const float*)d_in[11];
    const float* wh = (const float*)d_in[12]; const float* bh = (const float*)d_in[13];
    const float* wv = (const float*)d_in[14]; const float* bv = (const float*)d_in[15];

    float* out    = (float*)d_out;
    float* fin_o  = out;                    // [8,3,256,256]
    float* blur_o = out + 1572864;          // [8,3,256,256]
    float* kh_o   = out + 3145728;          // [8,11,256,256]
    float* kv_o   = out + 8912896;          // [8,11,256,256]
    float* mask_o = out + 14680064;         // [8,1,256,256]

    // --- Select batch group size G from ws_size (deterministic -> graph-safe).
    const size_t perG = (size_t)HW * 2 * (128 + 64 + 128);   // 41.9 MB per image
    const size_t wsz  = (size_t)1 * 1024 * 1024;
    int G = 1;
    if (ws_size >= 8 * perG + wsz) G = 8;
    else if (ws_size >= 4 * perG + wsz) G = 4;
    else if (ws_size >= 2 * perG + wsz) G = 2;

    char* ws = (char*)d_ws;
    const size_t szA = (size_t)G * HW * 128 * 2;
    const size_t szB = (size_t)G * HW * 64 * 2;
    const size_t szC = (size_t)G * HW * 128 * 2;
    bf16* bufA = (bf16*)ws;
    bf16* bufB = (bf16*)(ws + szA);
    bf16* bufC = (bf16*)(ws + szA + szB);
    float* hbuf = (float*)bufC;              // 6.3 MB <= szC

    bf16* w2r  = (bf16*)(ws + szA + szB + szC);
    bf16* w3r  = w2r + 9 * 64 * 64;
    bf16* w4r  = w3r + 9 * 128 * 64;
    bf16* w5r  = w4r + 9 * 128 * 128;
    bf16* whvr = w5r + 9 * 64 * 128;         // [9][32][64]

    dim3 blk(256);

    // one-time weight reorders (graph-safe: identical work every call)
    reorder_w<64, 64>  <<<dim3((9*64*64   + 255) / 256), blk, 0, stream>>>(w2, w2r);
    reorder_w<128, 64> <<<dim3((9*128*64  + 255) / 256), blk, 0, stream>>>(w3, w3r);
    reorder_w<128, 128><<<dim3((9*128*128 + 255) / 256), blk, 0, stream>>>(w4, w4r);
    reorder_w<64, 128> <<<dim3((9*64*128  + 255) / 256), blk, 0, stream>>>(w5, w5r);
    reorder_w_head2    <<<dim3((9*32*64   + 255) / 256), blk, 0, stream>>>(wh, wv, whvr);

    const int GY = 64 * G;
    for (int b0 = 0; b0 < BB; b0 += G) {
        conv3x3_first<16>            <<<dim3(4, GY, 4), blk, 0, stream>>>(rgb, depth, w1, b1, bufA, b0);
        conv_mfma_pipe<64, 64, 4, 4> <<<dim3(4, GY), blk, 0, stream>>>(bufA, w2r, b2, bufB);
        conv_mfma_pipe<64, 128, 8, 2><<<dim3(4, GY), blk, 0, stream>>>(bufB, w3r, b3, bufC);
        conv_mfma_pipe<128,128, 8, 2><<<dim3(4, GY), blk, 0, stream>>>(bufC, w4r, b4, bufA);
        conv_mfma_pipe<128, 64, 4, 4><<<dim3(4, GY), blk, 0, stream>>>(bufA, w5r, b5, bufB);
        head_mfma2                   <<<dim3(4, GY), blk, 0, stream>>>(bufB, whvr, bh, bv, kh_o, kv_o, b0);
    }

    // separable blur + composite (full batch; bufC/f3 dead by now)
    hpass<<<dim3(2048), blk, 0, stream>>>(rgb, kh_o, hbuf);
    vpass_compose<<<dim3(2048), blk, 0, stream>>>(hbuf, kv_o, rgb, depth,
                                                  fin_o, blur_o, mask_o);
}